// Round 1
// baseline (488.063 us; speedup 1.0000x reference)
//
#include <hip/hip_runtime.h>
#include <hip/hip_bf16.h>
#include <math.h>

// Problem constants (match reference)
#define NL   4
#define NH   8
#define DM   128
#define HDIM 16
#define FFD  256
#define SEQ  1024
#define BATCH 8
#define LWIN 128
#define NT   (BATCH*SEQ)      // 8192 tokens
#define EPSV 1e-5f

// ---------------------------------------------------------------------------
// Embedding + sinusoidal positional encoding
// x[t,d] = emb[token[t], d] + pe(s=t%SEQ, d)
// pe even d: sin(s * exp(-d*ln(10000)/128)); odd d: cos(same freq as d-1)
// ---------------------------------------------------------------------------
__global__ __launch_bounds__(256) void embed_kernel(
    const int* __restrict__ tok, const float* __restrict__ emb,
    float* __restrict__ x)
{
    int idx = blockIdx.x * 256 + threadIdx.x;     // 0 .. NT*DM-1
    int t = idx >> 7;
    int d = idx & 127;
    int s = t & (SEQ - 1);
    int token = tok[t];
    float freq = expf((float)(d & ~1) * (-9.210340371976184f / 128.0f));
    float ang = (float)s * freq;
    float pe = (d & 1) ? cosf(ang) : sinf(ang);
    x[idx] = emb[token * DM + d] + pe;
}

// ---------------------------------------------------------------------------
// Generic fp32 GEMM: C[M,N] = A[M,K] @ W[N,K]^T + bias[N], optional ReLU.
// 64x64 tile, BK=32, 256 threads, 4x4 microtile per thread.
// A staged k-major (stride 68) -> 16-distinct-row reads fully bank-spread.
// W staged row-major (stride 36) -> 4-distinct-col reads = 2-way (free).
// ---------------------------------------------------------------------------
#define GBM 64
#define GBN 64
#define GBK 32
#define ALDS_STR (GBM + 4)   // 68
#define WLDS_STR (GBK + 4)   // 36

__global__ __launch_bounds__(256) void gemm_kernel(
    const float* __restrict__ A, const float* __restrict__ W,
    const float* __restrict__ bias, float* __restrict__ C,
    int M, int N, int K, int relu)
{
    __shared__ float Alds[GBK * ALDS_STR];
    __shared__ float Wlds[GBN * WLDS_STR];

    int tid  = threadIdx.x;
    int row0 = blockIdx.x * GBM;
    int col0 = blockIdx.y * GBN;

    int ty = tid & 15;    // row group: rows 4*ty .. 4*ty+3
    int tx = tid >> 4;    // col group: cols 4*tx .. 4*tx+3

    float acc[4][4] = {{0.f}};

    for (int k0 = 0; k0 < K; k0 += GBK) {
        // --- stage A tile (k-major, transposed on write) ---
        {
            int r  = tid >> 3;           // 0..31
            int kg = (tid & 7) << 2;     // 0,4,...,28
            #pragma unroll
            for (int it = 0; it < 2; ++it) {
                int rr = r + it * 32;
                float4 a = *(const float4*)&A[(size_t)(row0 + rr) * K + k0 + kg];
                Alds[(kg + 0) * ALDS_STR + rr] = a.x;
                Alds[(kg + 1) * ALDS_STR + rr] = a.y;
                Alds[(kg + 2) * ALDS_STR + rr] = a.z;
                Alds[(kg + 3) * ALDS_STR + rr] = a.w;
            }
        }
        // --- stage W tile (row-major, padded) ---
        {
            int c  = tid >> 3;
            int kg = (tid & 7) << 2;
            #pragma unroll
            for (int it = 0; it < 2; ++it) {
                int cc = c + it * 32;
                float4 w = *(const float4*)&W[(size_t)(col0 + cc) * K + k0 + kg];
                *(float4*)&Wlds[cc * WLDS_STR + kg] = w;
            }
        }
        __syncthreads();

        #pragma unroll
        for (int k = 0; k < GBK; k += 4) {
            float a[4][4];   // [kk][row i]
            #pragma unroll
            for (int kk = 0; kk < 4; ++kk) {
                float4 v = *(const float4*)&Alds[(k + kk) * ALDS_STR + 4 * ty];
                a[kk][0] = v.x; a[kk][1] = v.y; a[kk][2] = v.z; a[kk][3] = v.w;
            }
            float w[4][4];   // [col j][kk]
            #pragma unroll
            for (int j = 0; j < 4; ++j) {
                float4 v = *(const float4*)&Wlds[(4 * tx + j) * WLDS_STR + k];
                w[j][0] = v.x; w[j][1] = v.y; w[j][2] = v.z; w[j][3] = v.w;
            }
            #pragma unroll
            for (int i = 0; i < 4; ++i)
                #pragma unroll
                for (int j = 0; j < 4; ++j)
                    #pragma unroll
                    for (int kk = 0; kk < 4; ++kk)
                        acc[i][j] = fmaf(a[kk][i], w[j][kk], acc[i][j]);
        }
        __syncthreads();
    }

    // epilogue: bias (+ReLU) + store
    float4 bv = *(const float4*)&bias[col0 + 4 * tx];
    #pragma unroll
    for (int i = 0; i < 4; ++i) {
        int r = row0 + 4 * ty + i;
        float4 o;
        o.x = acc[i][0] + bv.x;
        o.y = acc[i][1] + bv.y;
        o.z = acc[i][2] + bv.z;
        o.w = acc[i][3] + bv.w;
        if (relu) {
            o.x = fmaxf(o.x, 0.f); o.y = fmaxf(o.y, 0.f);
            o.z = fmaxf(o.z, 0.f); o.w = fmaxf(o.w, 0.f);
        }
        *(float4*)&C[(size_t)r * N + col0 + 4 * tx] = o;
    }
}

// ---------------------------------------------------------------------------
// Banded local attention. One block = one (b, h, 32-query tile).
// K/V window of 288 slots staged in LDS (stride 20 -> conflict-free for
// the 8-sub-lane slot interleave). 8 lanes cooperate per query; softmax
// reduced with shfl_xor over the low 3 lane bits.
// qkv layout: [token, 384] with q at col 0, k at 128, v at 256.
// ---------------------------------------------------------------------------
#define QB 32
#define KW (QB + 2 * LWIN)   // 288
#define KSTR 20

__global__ __launch_bounds__(256) void attn_kernel(
    const float* __restrict__ qkv, float* __restrict__ ctx)
{
    __shared__ float Klds[KW * KSTR];
    __shared__ float Vlds[KW * KSTR];

    int tid = threadIdx.x;
    int blk = blockIdx.x;
    int qb = blk & 31;            // S/QB = 32 tiles
    int h  = (blk >> 5) & 7;
    int b  = blk >> 8;
    int q0 = qb * QB;
    int kw0 = q0 - LWIN;

    // stage K and V window (zero out-of-range slots)
    for (int idx = tid; idx < KW * 4; idx += 256) {
        int slot = idx >> 2;
        int part = (idx & 3) << 2;
        int key = kw0 + slot;
        float4 kv = {0.f, 0.f, 0.f, 0.f}, vv = {0.f, 0.f, 0.f, 0.f};
        if (key >= 0 && key < SEQ) {
            size_t base = ((size_t)(b * SEQ + key)) * 384 + h * HDIM + part;
            kv = *(const float4*)&qkv[base + 128];
            vv = *(const float4*)&qkv[base + 256];
        }
        *(float4*)&Klds[slot * KSTR + part] = kv;
        *(float4*)&Vlds[slot * KSTR + part] = vv;
    }
    __syncthreads();

    int ql  = tid >> 3;     // 0..31 query within tile
    int sub = tid & 7;      // 0..7 cooperating lanes per query
    int q = q0 + ql;

    // load this query's 16 dims into registers
    float qv[16];
    {
        size_t base = ((size_t)(b * SEQ + q)) * 384 + h * HDIM;
        #pragma unroll
        for (int p = 0; p < 4; ++p) {
            float4 v = *(const float4*)&qkv[base + 4 * p];
            qv[4 * p + 0] = v.x; qv[4 * p + 1] = v.y;
            qv[4 * p + 2] = v.z; qv[4 * p + 3] = v.w;
        }
    }

    // scores for this lane's 36 interleaved slots
    float scr[36];
    float mx = -1e30f;
    #pragma unroll
    for (int j = 0; j < 36; ++j) {
        int slot = sub + 8 * j;
        int key = kw0 + slot;
        int dk = key - q;
        bool valid = (key >= 0) && (key < SEQ) && (dk <= LWIN) && (dk >= -LWIN);
        float s = -1e30f;
        if (valid) {
            const float* kp = &Klds[slot * KSTR];
            float d = 0.f;
            #pragma unroll
            for (int p = 0; p < 4; ++p) {
                float4 kk = *(const float4*)&kp[4 * p];
                d = fmaf(qv[4*p+0], kk.x, d);
                d = fmaf(qv[4*p+1], kk.y, d);
                d = fmaf(qv[4*p+2], kk.z, d);
                d = fmaf(qv[4*p+3], kk.w, d);
            }
            s = d * 0.25f;   // 1/sqrt(16)
        }
        scr[j] = s;
        mx = fmaxf(mx, s);
    }
    mx = fmaxf(mx, __shfl_xor(mx, 1));
    mx = fmaxf(mx, __shfl_xor(mx, 2));
    mx = fmaxf(mx, __shfl_xor(mx, 4));

    float sum = 0.f;
    #pragma unroll
    for (int j = 0; j < 36; ++j) {
        float p = __expf(scr[j] - mx);   // -1e30 -> exp -> exact 0
        scr[j] = p;
        sum += p;
    }
    sum += __shfl_xor(sum, 1);
    sum += __shfl_xor(sum, 2);
    sum += __shfl_xor(sum, 4);
    float inv = 1.0f / sum;

    // PV accumulate
    float acc[16] = {0.f};
    #pragma unroll
    for (int j = 0; j < 36; ++j) {
        int slot = sub + 8 * j;
        float p = scr[j];
        const float* vp = &Vlds[slot * KSTR];
        #pragma unroll
        for (int pp = 0; pp < 4; ++pp) {
            float4 v = *(const float4*)&vp[4 * pp];
            acc[4*pp+0] = fmaf(p, v.x, acc[4*pp+0]);
            acc[4*pp+1] = fmaf(p, v.y, acc[4*pp+1]);
            acc[4*pp+2] = fmaf(p, v.z, acc[4*pp+2]);
            acc[4*pp+3] = fmaf(p, v.w, acc[4*pp+3]);
        }
    }
    #pragma unroll
    for (int d = 0; d < 16; ++d) {
        acc[d] += __shfl_xor(acc[d], 1);
        acc[d] += __shfl_xor(acc[d], 2);
        acc[d] += __shfl_xor(acc[d], 4);
    }

    float2 o;
    o.x = acc[2 * sub + 0] * inv;
    o.y = acc[2 * sub + 1] * inv;
    *(float2*)&ctx[((size_t)(b * SEQ + q)) * DM + h * HDIM + 2 * sub] = o;
}

// ---------------------------------------------------------------------------
// Fused residual add + LayerNorm. One wave per row (D=128, 2 elems/lane).
// Safe in-place on x (each lane reads only what it writes).
// ---------------------------------------------------------------------------
__global__ __launch_bounds__(256) void add_ln_kernel(
    const float* __restrict__ xin, const float* __restrict__ add,
    const float* __restrict__ g, const float* __restrict__ bb,
    float* __restrict__ xout)
{
    int wave = threadIdx.x >> 6;
    int lane = threadIdx.x & 63;
    int row = blockIdx.x * 4 + wave;
    size_t base = (size_t)row * DM + lane * 2;

    float2 xv = *(const float2*)&xin[base];
    float2 av = *(const float2*)&add[base];
    float a = xv.x + av.x;
    float c = xv.y + av.y;
    float s = a + c, sq = a * a + c * c;
    #pragma unroll
    for (int m = 1; m < 64; m <<= 1) {
        s  += __shfl_xor(s, m);
        sq += __shfl_xor(sq, m);
    }
    float mean = s * (1.0f / 128.0f);
    float var = sq * (1.0f / 128.0f) - mean * mean;
    float rstd = rsqrtf(var + EPSV);
    float2 gv = *(const float2*)&g[lane * 2];
    float2 bv = *(const float2*)&bb[lane * 2];
    float2 o;
    o.x = (a - mean) * rstd * gv.x + bv.x;
    o.y = (c - mean) * rstd * gv.y + bv.y;
    *(float2*)&xout[base] = o;
}

// ---------------------------------------------------------------------------
// Final LN + out-projection (D->1) + softplus. One wave per row.
// ---------------------------------------------------------------------------
__global__ __launch_bounds__(256) void final_kernel(
    const float* __restrict__ x, const float* __restrict__ g,
    const float* __restrict__ bb, const float* __restrict__ Wout,
    const float* __restrict__ bout, float* __restrict__ out)
{
    int wave = threadIdx.x >> 6;
    int lane = threadIdx.x & 63;
    int row = blockIdx.x * 4 + wave;
    size_t base = (size_t)row * DM + lane * 2;

    float2 xv = *(const float2*)&x[base];
    float a = xv.x, c = xv.y;
    float s = a + c, sq = a * a + c * c;
    #pragma unroll
    for (int m = 1; m < 64; m <<= 1) {
        s  += __shfl_xor(s, m);
        sq += __shfl_xor(sq, m);
    }
    float mean = s * (1.0f / 128.0f);
    float var = sq * (1.0f / 128.0f) - mean * mean;
    float rstd = rsqrtf(var + EPSV);
    float2 gv = *(const float2*)&g[lane * 2];
    float2 bv = *(const float2*)&bb[lane * 2];
    float na = (a - mean) * rstd * gv.x + bv.x;
    float nc = (c - mean) * rstd * gv.y + bv.y;

    float2 wv = *(const float2*)&Wout[lane * 2];
    float d = na * wv.x + nc * wv.y;
    #pragma unroll
    for (int m = 1; m < 64; m <<= 1) d += __shfl_xor(d, m);

    if (lane == 0) {
        float z = d + bout[0];
        // stable softplus: max(z,0) + log1p(exp(-|z|))
        out[row] = fmaxf(z, 0.f) + log1pf(__expf(-fabsf(z)));
    }
}

// ---------------------------------------------------------------------------
extern "C" void kernel_launch(void* const* d_in, const int* in_sizes, int n_in,
                              void* d_out, int out_size, void* d_ws, size_t ws_size,
                              hipStream_t stream)
{
    const int*   tok  = (const int*)d_in[0];
    const float* emb  = (const float*)d_in[1];
    const float* Wqkv = (const float*)d_in[2];
    const float* bqkv = (const float*)d_in[3];
    const float* Wo   = (const float*)d_in[4];
    const float* bo   = (const float*)d_in[5];
    const float* ln1g = (const float*)d_in[6];
    const float* ln1b = (const float*)d_in[7];
    const float* ln2g = (const float*)d_in[8];
    const float* ln2b = (const float*)d_in[9];
    const float* W1   = (const float*)d_in[10];
    const float* b1   = (const float*)d_in[11];
    const float* W2   = (const float*)d_in[12];
    const float* b2   = (const float*)d_in[13];
    const float* lnfg = (const float*)d_in[14];
    const float* lnfb = (const float*)d_in[15];
    const float* Wout = (const float*)d_in[16];
    const float* bout = (const float*)d_in[17];
    float* out = (float*)d_out;

    float* ws  = (float*)d_ws;
    float* x   = ws;                          // NT*128
    float* qkv = x   + (size_t)NT * DM;       // NT*384
    float* ctx = qkv + (size_t)NT * 3 * DM;   // NT*128
    float* ffa = ctx + (size_t)NT * DM;       // NT*256
    float* tmp = ffa + (size_t)NT * FFD;      // NT*128

    embed_kernel<<<NT * DM / 256, 256, 0, stream>>>(tok, emb, x);

    for (int l = 0; l < NL; ++l) {
        gemm_kernel<<<dim3(NT / GBM, 3 * DM / GBN), 256, 0, stream>>>(
            x, Wqkv + (size_t)l * 3 * DM * DM, bqkv + l * 3 * DM, qkv,
            NT, 3 * DM, DM, 0);
        attn_kernel<<<BATCH * NH * (SEQ / QB), 256, 0, stream>>>(qkv, ctx);
        gemm_kernel<<<dim3(NT / GBM, DM / GBN), 256, 0, stream>>>(
            ctx, Wo + (size_t)l * DM * DM, bo + l * DM, tmp,
            NT, DM, DM, 0);
        add_ln_kernel<<<NT / 4, 256, 0, stream>>>(
            x, tmp, ln1g + l * DM, ln1b + l * DM, x);
        gemm_kernel<<<dim3(NT / GBM, FFD / GBN), 256, 0, stream>>>(
            x, W1 + (size_t)l * FFD * DM, b1 + l * FFD, ffa,
            NT, FFD, DM, 1);
        gemm_kernel<<<dim3(NT / GBM, DM / GBN), 256, 0, stream>>>(
            ffa, W2 + (size_t)l * DM * FFD, b2 + l * DM, tmp,
            NT, DM, FFD, 0);
        add_ln_kernel<<<NT / 4, 256, 0, stream>>>(
            x, tmp, ln2g + l * DM, ln2b + l * DM, x);
    }

    final_kernel<<<NT / 4, 256, 0, stream>>>(x, lnfg, lnfb, Wout, bout, out);
}

// Round 3
// 283.674 us; speedup vs baseline: 1.7205x; 1.7205x over previous
//
#include <hip/hip_runtime.h>
#include <hip/hip_bf16.h>
#include <math.h>

#define NL   4
#define NH   8
#define DM   128
#define FFD  256
#define SEQ  1024
#define BATCH 8
#define NT   (BATCH*SEQ)      // 8192 tokens
#define EPSV 1e-5f

typedef _Float16 h16;
typedef h16   h16x8 __attribute__((ext_vector_type(8)));
typedef float f32x4 __attribute__((ext_vector_type(4)));

// fp16 weight buffer segment offsets (elements)
#define WQKV_OFF 0
#define WO_OFF   196608
#define W1_OFF   262144
#define W2_OFF   393216
#define WTOT     524288

// ---------------------------------------------------------------------------
// fp32 -> fp16 weight conversion (all 4 weight tensors, all layers)
// ---------------------------------------------------------------------------
__global__ __launch_bounds__(256) void cvtw_kernel(
    const float* __restrict__ wqkv, const float* __restrict__ wo,
    const float* __restrict__ w1, const float* __restrict__ w2,
    h16* __restrict__ dst)
{
    int i = (blockIdx.x * 256 + threadIdx.x) * 4;
    const float* src; int off;
    if (i < WO_OFF)      { src = wqkv; off = 0; }
    else if (i < W1_OFF) { src = wo;   off = WO_OFF; }
    else if (i < W2_OFF) { src = w1;   off = W1_OFF; }
    else                 { src = w2;   off = W2_OFF; }
    float4 v = *(const float4*)&src[i - off];
    h16 o[4] = {(h16)v.x, (h16)v.y, (h16)v.z, (h16)v.w};
    *(uint2*)&dst[i] = *(uint2*)o;
}

// ---------------------------------------------------------------------------
// Embedding + sinusoidal PE -> x (fp32) and xh (fp16)
// ---------------------------------------------------------------------------
__global__ __launch_bounds__(256) void embed_kernel(
    const int* __restrict__ tok, const float* __restrict__ emb,
    float* __restrict__ x, h16* __restrict__ xh)
{
    int idx = blockIdx.x * 256 + threadIdx.x;
    int t = idx >> 7;
    int d = idx & 127;
    int s = t & (SEQ - 1);
    int token = tok[t];
    float freq = expf((float)(d & ~1) * (-9.210340371976184f / 128.0f));
    float ang = (float)s * freq;
    float pe = (d & 1) ? cosf(ang) : sinf(ang);
    float v = emb[token * DM + d] + pe;
    x[idx] = v;
    xh[idx] = (h16)v;
}

// ---------------------------------------------------------------------------
// fp16 MFMA GEMM: C[M,N] = A[M,K] @ W[N,K]^T + bias, optional ReLU.
// 64x64 tile, full-K staged in LDS (K=128 or 256), 4 waves, 2x2 frags of
// 16x16 each via mfma_f32_16x16x32_f16. Padded LDS stride (K+8 halves)
// keeps all fragment reads at <=2-way bank aliasing (free).
// ---------------------------------------------------------------------------
template<int KK, int RELU>
__global__ __launch_bounds__(256) void gemm16_kernel(
    const h16* __restrict__ A, const h16* __restrict__ W,
    const float* __restrict__ bias,
    float* __restrict__ out32, h16* __restrict__ out16, int N)
{
    constexpr int SA = KK + 8;      // halves per LDS row (16B-aligned stride)
    constexpr int CH = KK / 8;      // 16B chunks per row
    __shared__ h16 Al[64 * SA];
    __shared__ h16 Wl[64 * SA];

    int tid = threadIdx.x;
    long row0 = (long)blockIdx.x * 64;
    long col0 = (long)blockIdx.y * 64;

    for (int idx = tid; idx < 64 * CH; idx += 256) {
        int r = idx / CH, c = idx % CH;
        *(uint4*)&Al[r * SA + c * 8] = *(const uint4*)&A[(row0 + r) * KK + c * 8];
        *(uint4*)&Wl[r * SA + c * 8] = *(const uint4*)&W[(col0 + r) * KK + c * 8];
    }
    __syncthreads();

    int lane = tid & 63, wv = tid >> 6;
    int lr = lane & 15, lg = lane >> 4;
    int wr = (wv >> 1) * 32, wc = (wv & 1) * 32;

    f32x4 acc[2][2] = {{{0.f,0.f,0.f,0.f},{0.f,0.f,0.f,0.f}},
                       {{0.f,0.f,0.f,0.f},{0.f,0.f,0.f,0.f}}};

    #pragma unroll
    for (int k0 = 0; k0 < KK; k0 += 32) {
        h16x8 a0 = *(const h16x8*)&Al[(wr +      lr) * SA + k0 + lg * 8];
        h16x8 a1 = *(const h16x8*)&Al[(wr + 16 + lr) * SA + k0 + lg * 8];
        h16x8 b0 = *(const h16x8*)&Wl[(wc +      lr) * SA + k0 + lg * 8];
        h16x8 b1 = *(const h16x8*)&Wl[(wc + 16 + lr) * SA + k0 + lg * 8];
        acc[0][0] = __builtin_amdgcn_mfma_f32_16x16x32_f16(a0, b0, acc[0][0], 0, 0, 0);
        acc[0][1] = __builtin_amdgcn_mfma_f32_16x16x32_f16(a0, b1, acc[0][1], 0, 0, 0);
        acc[1][0] = __builtin_amdgcn_mfma_f32_16x16x32_f16(a1, b0, acc[1][0], 0, 0, 0);
        acc[1][1] = __builtin_amdgcn_mfma_f32_16x16x32_f16(a1, b1, acc[1][1], 0, 0, 0);
    }

    #pragma unroll
    for (int m = 0; m < 2; ++m)
    #pragma unroll
    for (int n = 0; n < 2; ++n) {
        long col = col0 + wc + 16 * n + lr;
        float bv = bias[col];
        #pragma unroll
        for (int r = 0; r < 4; ++r) {
            long row = row0 + wr + 16 * m + lg * 4 + r;
            float v = acc[m][n][r] + bv;
            if (RELU) v = fmaxf(v, 0.f);
            if (out32) out32[row * N + col] = v;
            if (out16) out16[row * N + col] = (h16)v;
        }
    }
}

// ---------------------------------------------------------------------------
// MFMA banded attention. Block = (b, h, 64 queries); 4 waves, each owns a
// 16-query tile. hd=16 zero-padded to K=32 for QK^T. 17 score tiles cover
// the 272-key union window; band mask is 2 compares on tiles {0,16} for
// interior blocks. Softmax on the D-layout (row = (lane>>4)*4+reg), P in
// LDS fp16 (unnormalized, <=1), PV via 9 MFMAs with V staged transposed.
// All LDS strides chosen for <=2-way bank aliasing.
// ---------------------------------------------------------------------------
#define NSLOT 336    // staged K/V slots per block (64 + 256 + 16 wave offset)
#define KSTR  24     // halves per K row (48B)
#define VSTR  344    // halves per Vt row (688B)
#define PSTR  296    // halves per P row (592B)

__global__ __launch_bounds__(256) void attn16_kernel(
    const h16* __restrict__ qkvh, h16* __restrict__ ctxh)
{
    __shared__ h16 Kl[NSLOT * KSTR];     // 16128 B
    __shared__ h16 Vt[16 * VSTR];        // 11008 B
    __shared__ h16 Pl[4 * 16 * PSTR];    // 37888 B

    int tid = threadIdx.x;
    int blk = blockIdx.x;
    int qb = blk & 15;
    int h  = (blk >> 4) & 7;
    int b  = blk >> 7;
    int q0b = qb * 64;
    int kw0 = q0b - 128;

    // ---- stage K rows (fp16, 32B per slot) ----
    for (int idx = tid; idx < NSLOT * 2; idx += 256) {
        int slot = idx >> 1, part = (idx & 1) * 8;
        int ka = kw0 + slot;
        uint4 val = {0u, 0u, 0u, 0u};
        if (ka >= 0 && ka < SEQ)
            val = *(const uint4*)&qkvh[((size_t)(b * SEQ + ka)) * 384 + h * 16 + 128 + part];
        *(uint4*)&Kl[slot * KSTR + part] = val;
    }
    // ---- stage V transposed: Vt[d][slot] ----
    for (int idx = tid; idx < NSLOT * 2; idx += 256) {
        int slot = idx >> 1, part = (idx & 1) * 8;
        int ka = kw0 + slot;
        uint4 val = {0u, 0u, 0u, 0u};
        if (ka >= 0 && ka < SEQ)
            val = *(const uint4*)&qkvh[((size_t)(b * SEQ + ka)) * 384 + h * 16 + 256 + part];
        h16 tmp[8];
        *(uint4*)tmp = val;
        #pragma unroll
        for (int j = 0; j < 8; ++j)
            Vt[(part + j) * VSTR + slot] = tmp[j];
    }
    __syncthreads();

    int lane = tid & 63, w = tid >> 6;
    int lr = lane & 15, lg = lane >> 4;
    int q0w = q0b + w * 16;

    // ---- Q fragment (row = lr, k = lg*8+i; zero for k>=16), pre-scaled ----
    h16x8 qf = {0, 0, 0, 0, 0, 0, 0, 0};
    if (lg < 2)
        qf = *(const h16x8*)&qkvh[((size_t)(b * SEQ + q0w + lr)) * 384 + h * 16 + lg * 8];
    qf = qf * (h16)0.25f;   // 1/sqrt(16), exact power of two

    // ---- QK^T: 17 score tiles ----
    f32x4 s[17];
    const f32x4 zero4 = {0.f, 0.f, 0.f, 0.f};
    #pragma unroll
    for (int t = 0; t < 17; ++t) {
        h16x8 kf = {0, 0, 0, 0, 0, 0, 0, 0};
        if (lg < 2)
            kf = *(const h16x8*)&Kl[(w * 16 + t * 16 + lr) * KSTR + lg * 8];
        s[t] = __builtin_amdgcn_mfma_f32_16x16x32_f16(qf, kf, zero4, 0, 0, 0);
    }

    // ---- band + sequence mask ----
    bool interior = (q0b >= 128) && (q0b <= 832);
    if (interior) {
        #pragma unroll
        for (int r = 0; r < 4; ++r) {
            int qr = lg * 4 + r;
            if (lr < qr) s[0][r]  = -1e30f;   // dk < -128
            if (lr > qr) s[16][r] = -1e30f;   // dk > +128
        }
    } else {
        #pragma unroll
        for (int t = 0; t < 17; ++t)
        #pragma unroll
        for (int r = 0; r < 4; ++r) {
            int rel = 16 * t + lr - (lg * 4 + r);   // dk + 128
            int ka  = kw0 + w * 16 + 16 * t + lr;
            bool valid = (rel >= 0) && (rel <= 256) && (ka >= 0) && (ka < SEQ);
            if (!valid) s[t][r] = -1e30f;
        }
    }

    // ---- softmax (rows spread over reg r; cols over lane&15) ----
    float mx[4] = {-1e30f, -1e30f, -1e30f, -1e30f};
    #pragma unroll
    for (int t = 0; t < 17; ++t)
        #pragma unroll
        for (int r = 0; r < 4; ++r) mx[r] = fmaxf(mx[r], s[t][r]);
    #pragma unroll
    for (int r = 0; r < 4; ++r) {
        mx[r] = fmaxf(mx[r], __shfl_xor(mx[r], 1));
        mx[r] = fmaxf(mx[r], __shfl_xor(mx[r], 2));
        mx[r] = fmaxf(mx[r], __shfl_xor(mx[r], 4));
        mx[r] = fmaxf(mx[r], __shfl_xor(mx[r], 8));
    }
    float sum[4] = {0.f, 0.f, 0.f, 0.f};
    #pragma unroll
    for (int t = 0; t < 17; ++t)
        #pragma unroll
        for (int r = 0; r < 4; ++r) {
            float p = __expf(s[t][r] - mx[r]);
            s[t][r] = p;
            sum[r] += p;
        }
    #pragma unroll
    for (int r = 0; r < 4; ++r) {
        sum[r] += __shfl_xor(sum[r], 1);
        sum[r] += __shfl_xor(sum[r], 2);
        sum[r] += __shfl_xor(sum[r], 4);
        sum[r] += __shfl_xor(sum[r], 8);
    }

    // ---- P -> LDS (fp16, unnormalized, p<=1); zero pad tile 17 ----
    h16* Pw = &Pl[w * 16 * PSTR];
    #pragma unroll
    for (int t = 0; t < 17; ++t)
        #pragma unroll
        for (int r = 0; r < 4; ++r)
            Pw[(lg * 4 + r) * PSTR + t * 16 + lr] = (h16)s[t][r];
    #pragma unroll
    for (int r = 0; r < 4; ++r)
        Pw[(lg * 4 + r) * PSTR + 272 + lr] = (h16)0.f;

    // ---- PV: 9 chunks of 32 keys ----
    f32x4 o = {0.f, 0.f, 0.f, 0.f};
    #pragma unroll
    for (int c = 0; c < 9; ++c) {
        h16x8 pf = *(const h16x8*)&Pw[lr * PSTR + c * 32 + lg * 8];
        h16x8 vf = *(const h16x8*)&Vt[lr * VSTR + w * 16 + c * 32 + lg * 8];
        o = __builtin_amdgcn_mfma_f32_16x16x32_f16(pf, vf, o, 0, 0, 0);
    }

    // ---- normalize + store ctx fp16 ----
    #pragma unroll
    for (int r = 0; r < 4; ++r) {
        float val = o[r] / sum[r];
        ctxh[((size_t)(b * SEQ + q0w + lg * 4 + r)) * DM + h * 16 + lr] = (h16)val;
    }
}

// ---------------------------------------------------------------------------
// Fused residual add + LayerNorm -> x (fp32) and xh (fp16). One wave/row.
// ---------------------------------------------------------------------------
__global__ __launch_bounds__(256) void add_ln_kernel(
    const float* __restrict__ xin, const float* __restrict__ add,
    const float* __restrict__ g, const float* __restrict__ bb,
    float* __restrict__ xout, h16* __restrict__ xh)
{
    int wave = threadIdx.x >> 6;
    int lane = threadIdx.x & 63;
    int row = blockIdx.x * 4 + wave;
    size_t base = (size_t)row * DM + lane * 2;

    float2 xv = *(const float2*)&xin[base];
    float2 av = *(const float2*)&add[base];
    float a = xv.x + av.x;
    float c = xv.y + av.y;
    float s = a + c, sq = a * a + c * c;
    #pragma unroll
    for (int m = 1; m < 64; m <<= 1) {
        s  += __shfl_xor(s, m);
        sq += __shfl_xor(sq, m);
    }
    float mean = s * (1.0f / 128.0f);
    float var = sq * (1.0f / 128.0f) - mean * mean;
    float rstd = rsqrtf(var + EPSV);
    float2 gv = *(const float2*)&g[lane * 2];
    float2 bv = *(const float2*)&bb[lane * 2];
    float2 o;
    o.x = (a - mean) * rstd * gv.x + bv.x;
    o.y = (c - mean) * rstd * gv.y + bv.y;
    *(float2*)&xout[base] = o;
    union { h16 hh[2]; unsigned u; } pk;
    pk.hh[0] = (h16)o.x; pk.hh[1] = (h16)o.y;
    *(unsigned*)&xh[base] = pk.u;
}

// ---------------------------------------------------------------------------
// Final LN + out-projection (D->1) + softplus. One wave per row.
// ---------------------------------------------------------------------------
__global__ __launch_bounds__(256) void final_kernel(
    const float* __restrict__ x, const float* __restrict__ g,
    const float* __restrict__ bb, const float* __restrict__ Wout,
    const float* __restrict__ bout, float* __restrict__ out)
{
    int wave = threadIdx.x >> 6;
    int lane = threadIdx.x & 63;
    int row = blockIdx.x * 4 + wave;
    size_t base = (size_t)row * DM + lane * 2;

    float2 xv = *(const float2*)&x[base];
    float a = xv.x, c = xv.y;
    float s = a + c, sq = a * a + c * c;
    #pragma unroll
    for (int m = 1; m < 64; m <<= 1) {
        s  += __shfl_xor(s, m);
        sq += __shfl_xor(sq, m);
    }
    float mean = s * (1.0f / 128.0f);
    float var = sq * (1.0f / 128.0f) - mean * mean;
    float rstd = rsqrtf(var + EPSV);
    float2 gv = *(const float2*)&g[lane * 2];
    float2 bv = *(const float2*)&bb[lane * 2];
    float na = (a - mean) * rstd * gv.x + bv.x;
    float nc = (c - mean) * rstd * gv.y + bv.y;

    float2 wv = *(const float2*)&Wout[lane * 2];
    float d = na * wv.x + nc * wv.y;
    #pragma unroll
    for (int m = 1; m < 64; m <<= 1) d += __shfl_xor(d, m);

    if (lane == 0) {
        float z = d + bout[0];
        out[row] = fmaxf(z, 0.f) + log1pf(__expf(-fabsf(z)));
    }
}

// ---------------------------------------------------------------------------
extern "C" void kernel_launch(void* const* d_in, const int* in_sizes, int n_in,
                              void* d_out, int out_size, void* d_ws, size_t ws_size,
                              hipStream_t stream)
{
    const int*   tok  = (const int*)d_in[0];
    const float* emb  = (const float*)d_in[1];
    const float* Wqkv = (const float*)d_in[2];
    const float* bqkv = (const float*)d_in[3];
    const float* Wo   = (const float*)d_in[4];
    const float* bo   = (const float*)d_in[5];
    const float* ln1g = (const float*)d_in[6];
    const float* ln1b = (const float*)d_in[7];
    const float* ln2g = (const float*)d_in[8];
    const float* ln2b = (const float*)d_in[9];
    const float* W1   = (const float*)d_in[10];
    const float* b1   = (const float*)d_in[11];
    const float* W2   = (const float*)d_in[12];
    const float* b2   = (const float*)d_in[13];
    const float* lnfg = (const float*)d_in[14];
    const float* lnfb = (const float*)d_in[15];
    const float* Wout = (const float*)d_in[16];
    const float* bout = (const float*)d_in[17];
    float* out = (float*)d_out;

    char* wsb = (char*)d_ws;
    float* x    = (float*)wsb;                        // NT*128 f32   (4 MB)
    h16*   xh   = (h16*)(wsb + 4194304);              // NT*128 h16   (2 MB)
    h16*   qkvh = (h16*)(wsb + 6291456);              // NT*384 h16   (6 MB)
    h16*   ctxh = (h16*)(wsb + 12582912);             // NT*128 h16   (2 MB)
    h16*   ffah = (h16*)(wsb + 14680064);             // NT*256 h16   (4 MB)
    float* tmp  = (float*)(wsb + 18874368);           // NT*128 f32   (4 MB)
    h16*   wh   = (h16*)(wsb + 23068672);             // 524288 h16   (1 MB)

    h16* Wqkv_h = wh + WQKV_OFF;
    h16* Wo_h   = wh + WO_OFF;
    h16* W1_h   = wh + W1_OFF;
    h16* W2_h   = wh + W2_OFF;

    cvtw_kernel<<<WTOT / 4 / 256, 256, 0, stream>>>(Wqkv, Wo, W1, W2, wh);
    embed_kernel<<<NT * DM / 256, 256, 0, stream>>>(tok, emb, x, xh);

    for (int l = 0; l < NL; ++l) {
        // QKV projection -> qkvh (fp16 only)
        gemm16_kernel<128, 0><<<dim3(NT / 64, 384 / 64), 256, 0, stream>>>(
            xh, Wqkv_h + (size_t)l * 384 * 128, bqkv + l * 384,
            nullptr, qkvh, 384);
        // banded attention -> ctxh (fp16)
        attn16_kernel<<<BATCH * NH * (SEQ / 64), 256, 0, stream>>>(qkvh, ctxh);
        // output projection -> tmp (fp32)
        gemm16_kernel<128, 0><<<dim3(NT / 64, 128 / 64), 256, 0, stream>>>(
            ctxh, Wo_h + (size_t)l * 128 * 128, bo + l * 128,
            tmp, nullptr, 128);
        add_ln_kernel<<<NT / 4, 256, 0, stream>>>(
            x, tmp, ln1g + l * DM, ln1b + l * DM, x, xh);
        // FF1 + ReLU -> ffah (fp16)
        gemm16_kernel<128, 1><<<dim3(NT / 64, 256 / 64), 256, 0, stream>>>(
            xh, W1_h + (size_t)l * 256 * 128, b1 + l * 256,
            nullptr, ffah, 256);
        // FF2 -> tmp (fp32)
        gemm16_kernel<256, 0><<<dim3(NT / 64, 128 / 64), 256, 0, stream>>>(
            ffah, W2_h + (size_t)l * 128 * 256, b2 + l * 128,
            tmp, nullptr, 128);
        add_ln_kernel<<<NT / 4, 256, 0, stream>>>(
            x, tmp, ln2g + l * DM, ln2b + l * DM, x, xh);
    }

    final_kernel<<<NT / 4, 256, 0, stream>>>(x, lnfg, lnfb, Wout, bout, out);
}

// Round 5
// 259.042 us; speedup vs baseline: 1.8841x; 1.0951x over previous
//
#include <hip/hip_runtime.h>
#include <hip/hip_bf16.h>
#include <math.h>

#define NL   4
#define NH   8
#define DM   128
#define FFD  256
#define SEQ  1024
#define BATCH 8
#define NT   (BATCH*SEQ)      // 8192 tokens
#define EPSV 1e-5f

typedef _Float16 h16;
typedef h16   h16x8 __attribute__((ext_vector_type(8)));
typedef float f32x4 __attribute__((ext_vector_type(4)));

// fp16 weight buffer segment offsets (elements)
#define WQKV_OFF 0
#define WO_OFF   196608
#define W1_OFF   262144
#define W2_OFF   393216
#define WTOT     524288

// ---------------------------------------------------------------------------
// fp32 -> fp16 weight conversion (all 4 weight tensors, all layers)
// ---------------------------------------------------------------------------
__global__ __launch_bounds__(256) void cvtw_kernel(
    const float* __restrict__ wqkv, const float* __restrict__ wo,
    const float* __restrict__ w1, const float* __restrict__ w2,
    h16* __restrict__ dst)
{
    int i = (blockIdx.x * 256 + threadIdx.x) * 4;
    const float* src; int off;
    if (i < WO_OFF)      { src = wqkv; off = 0; }
    else if (i < W1_OFF) { src = wo;   off = WO_OFF; }
    else if (i < W2_OFF) { src = w1;   off = W1_OFF; }
    else                 { src = w2;   off = W2_OFF; }
    float4 v = *(const float4*)&src[i - off];
    h16 o[4] = {(h16)v.x, (h16)v.y, (h16)v.z, (h16)v.w};
    *(uint2*)&dst[i] = *(uint2*)o;
}

// ---------------------------------------------------------------------------
// Embedding + sinusoidal PE -> x (fp32) and xh (fp16)
// ---------------------------------------------------------------------------
__global__ __launch_bounds__(256) void embed_kernel(
    const int* __restrict__ tok, const float* __restrict__ emb,
    float* __restrict__ x, h16* __restrict__ xh)
{
    int idx = blockIdx.x * 256 + threadIdx.x;
    int t = idx >> 7;
    int d = idx & 127;
    int s = t & (SEQ - 1);
    int token = tok[t];
    float freq = expf((float)(d & ~1) * (-9.210340371976184f / 128.0f));
    float ang = (float)s * freq;
    float pe = (d & 1) ? cosf(ang) : sinf(ang);
    float v = emb[token * DM + d] + pe;
    x[idx] = v;
    xh[idx] = (h16)v;
}

// ---------------------------------------------------------------------------
// fp16 MFMA GEMM (QKV only now): C = A[M,128] @ W[N,128]^T + bias -> fp16.
// 64x64 tile, 4 waves, 2x2 16x16 frags. Stride 136 halves -> <=2-way banks.
// ---------------------------------------------------------------------------
__global__ __launch_bounds__(256) void gemm16_kernel(
    const h16* __restrict__ A, const h16* __restrict__ W,
    const float* __restrict__ bias, h16* __restrict__ out16, int N)
{
    __shared__ h16 Al[64 * 136];
    __shared__ h16 Wl[64 * 136];

    int tid = threadIdx.x;
    long row0 = (long)blockIdx.x * 64;
    long col0 = (long)blockIdx.y * 64;

    for (int idx = tid; idx < 64 * 16; idx += 256) {
        int r = idx >> 4, c = idx & 15;
        *(uint4*)&Al[r * 136 + c * 8] = *(const uint4*)&A[(row0 + r) * 128 + c * 8];
        *(uint4*)&Wl[r * 136 + c * 8] = *(const uint4*)&W[(col0 + r) * 128 + c * 8];
    }
    __syncthreads();

    int lane = tid & 63, wv = tid >> 6;
    int lr = lane & 15, lg = lane >> 4;
    int wr = (wv >> 1) * 32, wc = (wv & 1) * 32;

    f32x4 acc[2][2] = {{{0.f,0.f,0.f,0.f},{0.f,0.f,0.f,0.f}},
                       {{0.f,0.f,0.f,0.f},{0.f,0.f,0.f,0.f}}};

    #pragma unroll
    for (int k0 = 0; k0 < 128; k0 += 32) {
        h16x8 a0 = *(const h16x8*)&Al[(wr +      lr) * 136 + k0 + lg * 8];
        h16x8 a1 = *(const h16x8*)&Al[(wr + 16 + lr) * 136 + k0 + lg * 8];
        h16x8 b0 = *(const h16x8*)&Wl[(wc +      lr) * 136 + k0 + lg * 8];
        h16x8 b1 = *(const h16x8*)&Wl[(wc + 16 + lr) * 136 + k0 + lg * 8];
        acc[0][0] = __builtin_amdgcn_mfma_f32_16x16x32_f16(a0, b0, acc[0][0], 0, 0, 0);
        acc[0][1] = __builtin_amdgcn_mfma_f32_16x16x32_f16(a0, b1, acc[0][1], 0, 0, 0);
        acc[1][0] = __builtin_amdgcn_mfma_f32_16x16x32_f16(a1, b0, acc[1][0], 0, 0, 0);
        acc[1][1] = __builtin_amdgcn_mfma_f32_16x16x32_f16(a1, b1, acc[1][1], 0, 0, 0);
    }

    #pragma unroll
    for (int m = 0; m < 2; ++m)
    #pragma unroll
    for (int n = 0; n < 2; ++n) {
        long col = col0 + wc + 16 * n + lr;
        float bv = bias[col];
        #pragma unroll
        for (int r = 0; r < 4; ++r) {
            long row = row0 + wr + 16 * m + lg * 4 + r;
            out16[row * N + col] = (h16)(acc[m][n][r] + bv);
        }
    }
}

// ---------------------------------------------------------------------------
// Shared epilogue: val = acc + bias + residual; LayerNorm across the 128-col
// row (2 waves per row -> cross-wave partial reduction via LDS); write x
// (fp32) and xh (fp16). Wave layout: 16 rows x 64 cols (4 col frags).
// ---------------------------------------------------------------------------
__device__ __forceinline__ void ln_epilogue(
    f32x4 acc[4], long row0, int wrow, int wcol, int lg, int lr, int w,
    const float* __restrict__ bias, const float* __restrict__ g,
    const float* __restrict__ bb, const float* __restrict__ xres,
    float* __restrict__ xo, h16* __restrict__ xho, float (*red)[2][2])
{
    float val[4][4];
    float bv[4];
    #pragma unroll
    for (int n = 0; n < 4; ++n) bv[n] = bias[wcol + 16 * n + lr];
    #pragma unroll
    for (int r = 0; r < 4; ++r) {
        long row = row0 + wrow + lg * 4 + r;
        #pragma unroll
        for (int n = 0; n < 4; ++n)
            val[r][n] = acc[n][r] + bv[n] + xres[row * 128 + wcol + 16 * n + lr];
    }
    float s[4], sq[4];
    #pragma unroll
    for (int r = 0; r < 4; ++r) {
        s[r]  = val[r][0] + val[r][1] + val[r][2] + val[r][3];
        sq[r] = val[r][0]*val[r][0] + val[r][1]*val[r][1]
              + val[r][2]*val[r][2] + val[r][3]*val[r][3];
        #pragma unroll
        for (int m = 1; m < 16; m <<= 1) {
            s[r]  += __shfl_xor(s[r], m);
            sq[r] += __shfl_xor(sq[r], m);
        }
    }
    int cg = w & 1;
    if (lr == 0) {
        #pragma unroll
        for (int r = 0; r < 4; ++r) {
            red[wrow + lg * 4 + r][cg][0] = s[r];
            red[wrow + lg * 4 + r][cg][1] = sq[r];
        }
    }
    __syncthreads();
    #pragma unroll
    for (int r = 0; r < 4; ++r) {
        int rowt = wrow + lg * 4 + r;
        float S  = red[rowt][0][0] + red[rowt][1][0];
        float SQ = red[rowt][0][1] + red[rowt][1][1];
        float mean = S * (1.0f / 128.0f);
        float var  = SQ * (1.0f / 128.0f) - mean * mean;
        float rstd = rsqrtf(var + EPSV);
        long row = row0 + rowt;
        #pragma unroll
        for (int n = 0; n < 4; ++n) {
            int col = wcol + 16 * n + lr;
            float o = (val[r][n] - mean) * rstd * g[col] + bb[col];
            xo[row * 128 + col]  = o;
            xho[row * 128 + col] = (h16)o;
        }
    }
}

// ---------------------------------------------------------------------------
// Fused Wo-projection + bias + residual + LN1. 32-row tile, 256 blocks,
// 4 waves (2 row-groups x 2 col-groups of 16x64).
// ---------------------------------------------------------------------------
__global__ __launch_bounds__(256) void wo_ln_kernel(
    const h16* __restrict__ ctx, const h16* __restrict__ Wo,
    const float* __restrict__ bo,
    const float* __restrict__ g, const float* __restrict__ bb,
    float* __restrict__ x, h16* __restrict__ xh)
{
    __shared__ h16 Xl[32 * 136];
    __shared__ h16 Wl[128 * 136];
    __shared__ float red[32][2][2];

    int tid = threadIdx.x;
    long row0 = (long)blockIdx.x * 32;

    for (int idx = tid; idx < 32 * 16; idx += 256) {
        int r = idx >> 4, c = idx & 15;
        *(uint4*)&Xl[r * 136 + c * 8] = *(const uint4*)&ctx[(row0 + r) * 128 + c * 8];
    }
    for (int idx = tid; idx < 128 * 16; idx += 256) {
        int r = idx >> 4, c = idx & 15;
        *(uint4*)&Wl[r * 136 + c * 8] = *(const uint4*)&Wo[r * 128 + c * 8];
    }
    __syncthreads();

    int lane = tid & 63, w = tid >> 6;
    int lr = lane & 15, lg = lane >> 4;
    int wrow = (w >> 1) * 16, wcol = (w & 1) * 64;

    f32x4 acc[4] = {{0.f,0.f,0.f,0.f},{0.f,0.f,0.f,0.f},
                    {0.f,0.f,0.f,0.f},{0.f,0.f,0.f,0.f}};
    #pragma unroll
    for (int k0 = 0; k0 < 128; k0 += 32) {
        h16x8 af = *(const h16x8*)&Xl[(wrow + lr) * 136 + k0 + lg * 8];
        #pragma unroll
        for (int n = 0; n < 4; ++n) {
            h16x8 bf = *(const h16x8*)&Wl[(wcol + 16 * n + lr) * 136 + k0 + lg * 8];
            acc[n] = __builtin_amdgcn_mfma_f32_16x16x32_f16(af, bf, acc[n], 0, 0, 0);
        }
    }

    ln_epilogue(acc, row0, wrow, wcol, lg, lr, w, bo, g, bb, x, x, xh, red);
}

// ---------------------------------------------------------------------------
// Fused FF1 + ReLU + FF2 + bias + residual + LN2. 32-row tile, 256 blocks.
// W1/W2 staged in 128-col/K halves through one reusable LDS buffer; the
// ReLU activation lives in LDS only (fp16, same rounding as before).
// ---------------------------------------------------------------------------
__global__ __launch_bounds__(256) void ff_ln_kernel(
    const h16* __restrict__ xh_in, const float* __restrict__ xres,
    const h16* __restrict__ W1, const float* __restrict__ b1,
    const h16* __restrict__ W2, const float* __restrict__ b2,
    const float* __restrict__ g, const float* __restrict__ bb,
    float* __restrict__ x_out, h16* __restrict__ xh_out)
{
    __shared__ h16 Xl[32 * 136];
    __shared__ h16 Wl[128 * 136];
    __shared__ h16 Al[32 * 136];
    __shared__ float red[32][2][2];

    int tid = threadIdx.x;
    long row0 = (long)blockIdx.x * 32;

    for (int idx = tid; idx < 32 * 16; idx += 256) {
        int r = idx >> 4, c = idx & 15;
        *(uint4*)&Xl[r * 136 + c * 8] = *(const uint4*)&xh_in[(row0 + r) * 128 + c * 8];
    }

    int lane = tid & 63, w = tid >> 6;
    int lr = lane & 15, lg = lane >> 4;
    int wrow = (w >> 1) * 16, wcol = (w & 1) * 64;

    f32x4 acc2[4] = {{0.f,0.f,0.f,0.f},{0.f,0.f,0.f,0.f},
                     {0.f,0.f,0.f,0.f},{0.f,0.f,0.f,0.f}};

    #pragma unroll 1
    for (int half = 0; half < 2; ++half) {
        __syncthreads();   // Xl staged (h0) / Wl free of FF2 readers (h1)
        for (int idx = tid; idx < 128 * 16; idx += 256) {
            int r = idx >> 4, c = idx & 15;
            *(uint4*)&Wl[r * 136 + c * 8] =
                *(const uint4*)&W1[(128 * half + r) * 128 + c * 8];
        }
        __syncthreads();

        // FF1 half: a = relu(x1 @ W1h^T + b1h)
        f32x4 acc1[4] = {{0.f,0.f,0.f,0.f},{0.f,0.f,0.f,0.f},
                         {0.f,0.f,0.f,0.f},{0.f,0.f,0.f,0.f}};
        #pragma unroll
        for (int k0 = 0; k0 < 128; k0 += 32) {
            h16x8 af = *(const h16x8*)&Xl[(wrow + lr) * 136 + k0 + lg * 8];
            #pragma unroll
            for (int n = 0; n < 4; ++n) {
                h16x8 bf = *(const h16x8*)&Wl[(wcol + 16 * n + lr) * 136 + k0 + lg * 8];
                acc1[n] = __builtin_amdgcn_mfma_f32_16x16x32_f16(af, bf, acc1[n], 0, 0, 0);
            }
        }
        __syncthreads();   // all FF1 reads of Wl done -> Wl reusable; Al free

        // write activation to LDS (fp16) + stage W2 half
        #pragma unroll
        for (int r = 0; r < 4; ++r)
            #pragma unroll
            for (int n = 0; n < 4; ++n) {
                int col = wcol + 16 * n + lr;
                float v = acc1[n][r] + b1[128 * half + col];
                Al[(wrow + lg * 4 + r) * 136 + col] = (h16)fmaxf(v, 0.f);
            }
        for (int idx = tid; idx < 128 * 16; idx += 256) {
            int r = idx >> 4, c = idx & 15;
            *(uint4*)&Wl[r * 136 + c * 8] =
                *(const uint4*)&W2[r * 256 + 128 * half + c * 8];
        }
        __syncthreads();

        // FF2 half: acc2 += a @ W2h^T
        #pragma unroll
        for (int k0 = 0; k0 < 128; k0 += 32) {
            h16x8 af = *(const h16x8*)&Al[(wrow + lr) * 136 + k0 + lg * 8];
            #pragma unroll
            for (int n = 0; n < 4; ++n) {
                h16x8 bf = *(const h16x8*)&Wl[(wcol + 16 * n + lr) * 136 + k0 + lg * 8];
                acc2[n] = __builtin_amdgcn_mfma_f32_16x16x32_f16(af, bf, acc2[n], 0, 0, 0);
            }
        }
    }

    ln_epilogue(acc2, row0, wrow, wcol, lg, lr, w, b2, g, bb, xres, x_out, xh_out, red);
}

// ---------------------------------------------------------------------------
// MFMA banded attention (unchanged, proven).
// ---------------------------------------------------------------------------
#define NSLOT 336
#define KSTR  24
#define VSTR  344
#define PSTR  296

__global__ __launch_bounds__(256) void attn16_kernel(
    const h16* __restrict__ qkvh, h16* __restrict__ ctxh)
{
    __shared__ h16 Kl[NSLOT * KSTR];
    __shared__ h16 Vt[16 * VSTR];
    __shared__ h16 Pl[4 * 16 * PSTR];

    int tid = threadIdx.x;
    int blk = blockIdx.x;
    int qb = blk & 15;
    int h  = (blk >> 4) & 7;
    int b  = blk >> 7;
    int q0b = qb * 64;
    int kw0 = q0b - 128;

    for (int idx = tid; idx < NSLOT * 2; idx += 256) {
        int slot = idx >> 1, part = (idx & 1) * 8;
        int ka = kw0 + slot;
        uint4 val = {0u, 0u, 0u, 0u};
        if (ka >= 0 && ka < SEQ)
            val = *(const uint4*)&qkvh[((size_t)(b * SEQ + ka)) * 384 + h * 16 + 128 + part];
        *(uint4*)&Kl[slot * KSTR + part] = val;
    }
    for (int idx = tid; idx < NSLOT * 2; idx += 256) {
        int slot = idx >> 1, part = (idx & 1) * 8;
        int ka = kw0 + slot;
        uint4 val = {0u, 0u, 0u, 0u};
        if (ka >= 0 && ka < SEQ)
            val = *(const uint4*)&qkvh[((size_t)(b * SEQ + ka)) * 384 + h * 16 + 256 + part];
        h16 tmp[8];
        *(uint4*)tmp = val;
        #pragma unroll
        for (int j = 0; j < 8; ++j)
            Vt[(part + j) * VSTR + slot] = tmp[j];
    }
    __syncthreads();

    int lane = tid & 63, w = tid >> 6;
    int lr = lane & 15, lg = lane >> 4;
    int q0w = q0b + w * 16;

    h16x8 qf = {0, 0, 0, 0, 0, 0, 0, 0};
    if (lg < 2)
        qf = *(const h16x8*)&qkvh[((size_t)(b * SEQ + q0w + lr)) * 384 + h * 16 + lg * 8];
    qf = qf * (h16)0.25f;

    f32x4 s[17];
    const f32x4 zero4 = {0.f, 0.f, 0.f, 0.f};
    #pragma unroll
    for (int t = 0; t < 17; ++t) {
        h16x8 kf = {0, 0, 0, 0, 0, 0, 0, 0};
        if (lg < 2)
            kf = *(const h16x8*)&Kl[(w * 16 + t * 16 + lr) * KSTR + lg * 8];
        s[t] = __builtin_amdgcn_mfma_f32_16x16x32_f16(qf, kf, zero4, 0, 0, 0);
    }

    bool interior = (q0b >= 128) && (q0b <= 832);
    if (interior) {
        #pragma unroll
        for (int r = 0; r < 4; ++r) {
            int qr = lg * 4 + r;
            if (lr < qr) s[0][r]  = -1e30f;
            if (lr > qr) s[16][r] = -1e30f;
        }
    } else {
        #pragma unroll
        for (int t = 0; t < 17; ++t)
        #pragma unroll
        for (int r = 0; r < 4; ++r) {
            int rel = 16 * t + lr - (lg * 4 + r);
            int ka  = kw0 + w * 16 + 16 * t + lr;
            bool valid = (rel >= 0) && (rel <= 256) && (ka >= 0) && (ka < SEQ);
            if (!valid) s[t][r] = -1e30f;
        }
    }

    float mx[4] = {-1e30f, -1e30f, -1e30f, -1e30f};
    #pragma unroll
    for (int t = 0; t < 17; ++t)
        #pragma unroll
        for (int r = 0; r < 4; ++r) mx[r] = fmaxf(mx[r], s[t][r]);
    #pragma unroll
    for (int r = 0; r < 4; ++r) {
        mx[r] = fmaxf(mx[r], __shfl_xor(mx[r], 1));
        mx[r] = fmaxf(mx[r], __shfl_xor(mx[r], 2));
        mx[r] = fmaxf(mx[r], __shfl_xor(mx[r], 4));
        mx[r] = fmaxf(mx[r], __shfl_xor(mx[r], 8));
    }
    float sum[4] = {0.f, 0.f, 0.f, 0.f};
    #pragma unroll
    for (int t = 0; t < 17; ++t)
        #pragma unroll
        for (int r = 0; r < 4; ++r) {
            float p = __expf(s[t][r] - mx[r]);
            s[t][r] = p;
            sum[r] += p;
        }
    #pragma unroll
    for (int r = 0; r < 4; ++r) {
        sum[r] += __shfl_xor(sum[r], 1);
        sum[r] += __shfl_xor(sum[r], 2);
        sum[r] += __shfl_xor(sum[r], 4);
        sum[r] += __shfl_xor(sum[r], 8);
    }

    h16* Pw = &Pl[w * 16 * PSTR];
    #pragma unroll
    for (int t = 0; t < 17; ++t)
        #pragma unroll
        for (int r = 0; r < 4; ++r)
            Pw[(lg * 4 + r) * PSTR + t * 16 + lr] = (h16)s[t][r];
    #pragma unroll
    for (int r = 0; r < 4; ++r)
        Pw[(lg * 4 + r) * PSTR + 272 + lr] = (h16)0.f;

    f32x4 o = {0.f, 0.f, 0.f, 0.f};
    #pragma unroll
    for (int c = 0; c < 9; ++c) {
        h16x8 pf = *(const h16x8*)&Pw[lr * PSTR + c * 32 + lg * 8];
        h16x8 vf = *(const h16x8*)&Vt[lr * VSTR + w * 16 + c * 32 + lg * 8];
        o = __builtin_amdgcn_mfma_f32_16x16x32_f16(pf, vf, o, 0, 0, 0);
    }

    #pragma unroll
    for (int r = 0; r < 4; ++r) {
        float val = o[r] / sum[r];
        ctxh[((size_t)(b * SEQ + q0w + lg * 4 + r)) * DM + h * 16 + lr] = (h16)val;
    }
}

// ---------------------------------------------------------------------------
// Final LN + out-projection (D->1) + softplus. One wave per row.
// ---------------------------------------------------------------------------
__global__ __launch_bounds__(256) void final_kernel(
    const float* __restrict__ x, const float* __restrict__ g,
    const float* __restrict__ bb, const float* __restrict__ Wout,
    const float* __restrict__ bout, float* __restrict__ out)
{
    int wave = threadIdx.x >> 6;
    int lane = threadIdx.x & 63;
    int row = blockIdx.x * 4 + wave;
    size_t base = (size_t)row * DM + lane * 2;

    float2 xv = *(const float2*)&x[base];
    float a = xv.x, c = xv.y;
    float s = a + c, sq = a * a + c * c;
    #pragma unroll
    for (int m = 1; m < 64; m <<= 1) {
        s  += __shfl_xor(s, m);
        sq += __shfl_xor(sq, m);
    }
    float mean = s * (1.0f / 128.0f);
    float var = sq * (1.0f / 128.0f) - mean * mean;
    float rstd = rsqrtf(var + EPSV);
    float2 gv = *(const float2*)&g[lane * 2];
    float2 bv = *(const float2*)&bb[lane * 2];
    float na = (a - mean) * rstd * gv.x + bv.x;
    float nc = (c - mean) * rstd * gv.y + bv.y;

    float2 wv = *(const float2*)&Wout[lane * 2];
    float d = na * wv.x + nc * wv.y;
    #pragma unroll
    for (int m = 1; m < 64; m <<= 1) d += __shfl_xor(d, m);

    if (lane == 0) {
        float z = d + bout[0];
        out[row] = fmaxf(z, 0.f) + log1pf(__expf(-fabsf(z)));
    }
}

// ---------------------------------------------------------------------------
extern "C" void kernel_launch(void* const* d_in, const int* in_sizes, int n_in,
                              void* d_out, int out_size, void* d_ws, size_t ws_size,
                              hipStream_t stream)
{
    const int*   tok  = (const int*)d_in[0];
    const float* emb  = (const float*)d_in[1];
    const float* Wqkv = (const float*)d_in[2];
    const float* bqkv = (const float*)d_in[3];
    const float* Wo   = (const float*)d_in[4];
    const float* bo   = (const float*)d_in[5];
    const float* ln1g = (const float*)d_in[6];
    const float* ln1b = (const float*)d_in[7];
    const float* ln2g = (const float*)d_in[8];
    const float* ln2b = (const float*)d_in[9];
    const float* W1   = (const float*)d_in[10];
    const float* b1   = (const float*)d_in[11];
    const float* W2   = (const float*)d_in[12];
    const float* b2   = (const float*)d_in[13];
    const float* lnfg = (const float*)d_in[14];
    const float* lnfb = (const float*)d_in[15];
    const float* Wout = (const float*)d_in[16];
    const float* bout = (const float*)d_in[17];
    float* out = (float*)d_out;

    char* wsb = (char*)d_ws;
    float* x    = (float*)wsb;                        // NT*128 f32   (4 MB)
    h16*   xh   = (h16*)(wsb + 4194304);              // NT*128 h16   (2 MB)
    h16*   qkvh = (h16*)(wsb + 6291456);              // NT*384 h16   (6 MB)
    h16*   ctxh = (h16*)(wsb + 12582912);             // NT*128 h16   (2 MB)
    h16*   wh   = (h16*)(wsb + 14680064);             // 524288 h16   (1 MB)

    h16* Wqkv_h = wh + WQKV_OFF;
    h16* Wo_h   = wh + WO_OFF;
    h16* W1_h   = wh + W1_OFF;
    h16* W2_h   = wh + W2_OFF;

    cvtw_kernel<<<WTOT / 4 / 256, 256, 0, stream>>>(Wqkv, Wo, W1, W2, wh);
    embed_kernel<<<NT * DM / 256, 256, 0, stream>>>(tok, emb, x, xh);

    for (int l = 0; l < NL; ++l) {
        gemm16_kernel<<<dim3(NT / 64, 384 / 64), 256, 0, stream>>>(
            xh, Wqkv_h + (size_t)l * 384 * 128, bqkv + l * 384, qkvh, 384);
        attn16_kernel<<<BATCH * NH * (SEQ / 64), 256, 0, stream>>>(qkvh, ctxh);
        wo_ln_kernel<<<NT / 32, 256, 0, stream>>>(
            ctxh, Wo_h + (size_t)l * 128 * 128, bo + l * 128,
            ln1g + l * DM, ln1b + l * DM, x, xh);
        ff_ln_kernel<<<NT / 32, 256, 0, stream>>>(
            xh, x,
            W1_h + (size_t)l * 256 * 128, b1 + l * 256,
            W2_h + (size_t)l * 128 * 256, b2 + l * 128,
            ln2g + l * DM, ln2b + l * DM, x, xh);
    }

    final_kernel<<<NT / 4, 256, 0, stream>>>(x, lnfg, lnfb, Wout, bout, out);
}

// Round 6
// 245.115 us; speedup vs baseline: 1.9912x; 1.0568x over previous
//
#include <hip/hip_runtime.h>
#include <hip/hip_bf16.h>
#include <math.h>

#define NL   4
#define NH   8
#define DM   128
#define FFD  256
#define SEQ  1024
#define BATCH 8
#define NT   (BATCH*SEQ)      // 8192 tokens
#define EPSV 1e-5f

typedef _Float16 h16;
typedef h16   h16x8 __attribute__((ext_vector_type(8)));
typedef float f32x4 __attribute__((ext_vector_type(4)));

// fp16 weight buffer segment offsets (elements)
#define WQKV_OFF 0
#define WO_OFF   196608
#define W1_OFF   262144
#define W2_OFF   393216
#define WTOT     524288

// ---------------------------------------------------------------------------
// Fused prep: embed+PE (blocks 0..4095) and weight fp32->fp16 (blocks 4096+)
// ---------------------------------------------------------------------------
__global__ __launch_bounds__(256) void prep_kernel(
    const int* __restrict__ tok, const float* __restrict__ emb,
    float* __restrict__ x, h16* __restrict__ xh,
    const float* __restrict__ wqkv, const float* __restrict__ wo,
    const float* __restrict__ w1, const float* __restrict__ w2,
    h16* __restrict__ wdst)
{
    int bid = blockIdx.x;
    if (bid < 4096) {
        int idx = bid * 256 + threadIdx.x;
        int t = idx >> 7;
        int d = idx & 127;
        int s = t & (SEQ - 1);
        int token = tok[t];
        float freq = expf((float)(d & ~1) * (-9.210340371976184f / 128.0f));
        float ang = (float)s * freq;
        float pe = (d & 1) ? cosf(ang) : sinf(ang);
        float v = emb[token * DM + d] + pe;
        x[idx] = v;
        xh[idx] = (h16)v;
    } else {
        int i = ((bid - 4096) * 256 + threadIdx.x) * 4;
        const float* src; int off;
        if (i < WO_OFF)      { src = wqkv; off = 0; }
        else if (i < W1_OFF) { src = wo;   off = WO_OFF; }
        else if (i < W2_OFF) { src = w1;   off = W1_OFF; }
        else                 { src = w2;   off = W2_OFF; }
        float4 v = *(const float4*)&src[i - off];
        h16 o[4] = {(h16)v.x, (h16)v.y, (h16)v.z, (h16)v.w};
        *(uint2*)&wdst[i] = *(uint2*)o;
    }
}

// ---------------------------------------------------------------------------
// fp16 MFMA GEMM (QKV): C = A[M,128] @ W[N,128]^T + bias -> fp16. (proven)
// ---------------------------------------------------------------------------
__global__ __launch_bounds__(256) void gemm16_kernel(
    const h16* __restrict__ A, const h16* __restrict__ W,
    const float* __restrict__ bias, h16* __restrict__ out16, int N)
{
    __shared__ h16 Al[64 * 136];
    __shared__ h16 Wl[64 * 136];

    int tid = threadIdx.x;
    long row0 = (long)blockIdx.x * 64;
    long col0 = (long)blockIdx.y * 64;

    for (int idx = tid; idx < 64 * 16; idx += 256) {
        int r = idx >> 4, c = idx & 15;
        *(uint4*)&Al[r * 136 + c * 8] = *(const uint4*)&A[(row0 + r) * 128 + c * 8];
        *(uint4*)&Wl[r * 136 + c * 8] = *(const uint4*)&W[(col0 + r) * 128 + c * 8];
    }
    __syncthreads();

    int lane = tid & 63, wv = tid >> 6;
    int lr = lane & 15, lg = lane >> 4;
    int wr = (wv >> 1) * 32, wc = (wv & 1) * 32;

    f32x4 acc[2][2] = {{{0.f,0.f,0.f,0.f},{0.f,0.f,0.f,0.f}},
                       {{0.f,0.f,0.f,0.f},{0.f,0.f,0.f,0.f}}};

    #pragma unroll
    for (int k0 = 0; k0 < 128; k0 += 32) {
        h16x8 a0 = *(const h16x8*)&Al[(wr +      lr) * 136 + k0 + lg * 8];
        h16x8 a1 = *(const h16x8*)&Al[(wr + 16 + lr) * 136 + k0 + lg * 8];
        h16x8 b0 = *(const h16x8*)&Wl[(wc +      lr) * 136 + k0 + lg * 8];
        h16x8 b1 = *(const h16x8*)&Wl[(wc + 16 + lr) * 136 + k0 + lg * 8];
        acc[0][0] = __builtin_amdgcn_mfma_f32_16x16x32_f16(a0, b0, acc[0][0], 0, 0, 0);
        acc[0][1] = __builtin_amdgcn_mfma_f32_16x16x32_f16(a0, b1, acc[0][1], 0, 0, 0);
        acc[1][0] = __builtin_amdgcn_mfma_f32_16x16x32_f16(a1, b0, acc[1][0], 0, 0, 0);
        acc[1][1] = __builtin_amdgcn_mfma_f32_16x16x32_f16(a1, b1, acc[1][1], 0, 0, 0);
    }

    #pragma unroll
    for (int m = 0; m < 2; ++m)
    #pragma unroll
    for (int n = 0; n < 2; ++n) {
        long col = col0 + wc + 16 * n + lr;
        float bv = bias[col];
        #pragma unroll
        for (int r = 0; r < 4; ++r) {
            long row = row0 + wr + 16 * m + lg * 4 + r;
            out16[row * N + col] = (h16)(acc[m][n][r] + bv);
        }
    }
}

// ---------------------------------------------------------------------------
// MFMA banded attention (unchanged, proven).
// ---------------------------------------------------------------------------
#define NSLOT 336
#define KSTR  24
#define VSTR  344
#define PSTR  296

__global__ __launch_bounds__(256) void attn16_kernel(
    const h16* __restrict__ qkvh, h16* __restrict__ ctxh)
{
    __shared__ h16 Kl[NSLOT * KSTR];
    __shared__ h16 Vt[16 * VSTR];
    __shared__ h16 Pl[4 * 16 * PSTR];

    int tid = threadIdx.x;
    int blk = blockIdx.x;
    int qb = blk & 15;
    int h  = (blk >> 4) & 7;
    int b  = blk >> 7;
    int q0b = qb * 64;
    int kw0 = q0b - 128;

    for (int idx = tid; idx < NSLOT * 2; idx += 256) {
        int slot = idx >> 1, part = (idx & 1) * 8;
        int ka = kw0 + slot;
        uint4 val = {0u, 0u, 0u, 0u};
        if (ka >= 0 && ka < SEQ)
            val = *(const uint4*)&qkvh[((size_t)(b * SEQ + ka)) * 384 + h * 16 + 128 + part];
        *(uint4*)&Kl[slot * KSTR + part] = val;
    }
    for (int idx = tid; idx < NSLOT * 2; idx += 256) {
        int slot = idx >> 1, part = (idx & 1) * 8;
        int ka = kw0 + slot;
        uint4 val = {0u, 0u, 0u, 0u};
        if (ka >= 0 && ka < SEQ)
            val = *(const uint4*)&qkvh[((size_t)(b * SEQ + ka)) * 384 + h * 16 + 256 + part];
        h16 tmp[8];
        *(uint4*)tmp = val;
        #pragma unroll
        for (int j = 0; j < 8; ++j)
            Vt[(part + j) * VSTR + slot] = tmp[j];
    }
    __syncthreads();

    int lane = tid & 63, w = tid >> 6;
    int lr = lane & 15, lg = lane >> 4;
    int q0w = q0b + w * 16;

    h16x8 qf = {0, 0, 0, 0, 0, 0, 0, 0};
    if (lg < 2)
        qf = *(const h16x8*)&qkvh[((size_t)(b * SEQ + q0w + lr)) * 384 + h * 16 + lg * 8];
    qf = qf * (h16)0.25f;

    f32x4 s[17];
    const f32x4 zero4 = {0.f, 0.f, 0.f, 0.f};
    #pragma unroll
    for (int t = 0; t < 17; ++t) {
        h16x8 kf = {0, 0, 0, 0, 0, 0, 0, 0};
        if (lg < 2)
            kf = *(const h16x8*)&Kl[(w * 16 + t * 16 + lr) * KSTR + lg * 8];
        s[t] = __builtin_amdgcn_mfma_f32_16x16x32_f16(qf, kf, zero4, 0, 0, 0);
    }

    bool interior = (q0b >= 128) && (q0b <= 832);
    if (interior) {
        #pragma unroll
        for (int r = 0; r < 4; ++r) {
            int qr = lg * 4 + r;
            if (lr < qr) s[0][r]  = -1e30f;
            if (lr > qr) s[16][r] = -1e30f;
        }
    } else {
        #pragma unroll
        for (int t = 0; t < 17; ++t)
        #pragma unroll
        for (int r = 0; r < 4; ++r) {
            int rel = 16 * t + lr - (lg * 4 + r);
            int ka  = kw0 + w * 16 + 16 * t + lr;
            bool valid = (rel >= 0) && (rel <= 256) && (ka >= 0) && (ka < SEQ);
            if (!valid) s[t][r] = -1e30f;
        }
    }

    float mx[4] = {-1e30f, -1e30f, -1e30f, -1e30f};
    #pragma unroll
    for (int t = 0; t < 17; ++t)
        #pragma unroll
        for (int r = 0; r < 4; ++r) mx[r] = fmaxf(mx[r], s[t][r]);
    #pragma unroll
    for (int r = 0; r < 4; ++r) {
        mx[r] = fmaxf(mx[r], __shfl_xor(mx[r], 1));
        mx[r] = fmaxf(mx[r], __shfl_xor(mx[r], 2));
        mx[r] = fmaxf(mx[r], __shfl_xor(mx[r], 4));
        mx[r] = fmaxf(mx[r], __shfl_xor(mx[r], 8));
    }
    float sum[4] = {0.f, 0.f, 0.f, 0.f};
    #pragma unroll
    for (int t = 0; t < 17; ++t)
        #pragma unroll
        for (int r = 0; r < 4; ++r) {
            float p = __expf(s[t][r] - mx[r]);
            s[t][r] = p;
            sum[r] += p;
        }
    #pragma unroll
    for (int r = 0; r < 4; ++r) {
        sum[r] += __shfl_xor(sum[r], 1);
        sum[r] += __shfl_xor(sum[r], 2);
        sum[r] += __shfl_xor(sum[r], 4);
        sum[r] += __shfl_xor(sum[r], 8);
    }

    h16* Pw = &Pl[w * 16 * PSTR];
    #pragma unroll
    for (int t = 0; t < 17; ++t)
        #pragma unroll
        for (int r = 0; r < 4; ++r)
            Pw[(lg * 4 + r) * PSTR + t * 16 + lr] = (h16)s[t][r];
    #pragma unroll
    for (int r = 0; r < 4; ++r)
        Pw[(lg * 4 + r) * PSTR + 272 + lr] = (h16)0.f;

    f32x4 o = {0.f, 0.f, 0.f, 0.f};
    #pragma unroll
    for (int c = 0; c < 9; ++c) {
        h16x8 pf = *(const h16x8*)&Pw[lr * PSTR + c * 32 + lg * 8];
        h16x8 vf = *(const h16x8*)&Vt[lr * VSTR + w * 16 + c * 32 + lg * 8];
        o = __builtin_amdgcn_mfma_f32_16x16x32_f16(pf, vf, o, 0, 0, 0);
    }

    #pragma unroll
    for (int r = 0; r < 4; ++r) {
        float val = o[r] / sum[r];
        ctxh[((size_t)(b * SEQ + q0w + lg * 4 + r)) * DM + h * 16 + lr] = (h16)val;
    }
}

// ---------------------------------------------------------------------------
// Fused layer tail: Wo-proj + bias + residual + LN1 + FF1 + ReLU + FF2 +
// bias + residual + LN2 (+ final LN + out-proj + softplus when LAST).
// 32-row tile, 256 blocks, 4 waves (2 row-groups x 2 col-groups of 16x64).
// LN1 output kept in registers (residual for LN2) and written fp16 to Xl
// (FF1 A-operand). W weights staged through one reusable 34.8KB LDS buffer.
// Arithmetic path identical to the unfused Round-5 kernels.
// ---------------------------------------------------------------------------
template<int LAST>
__global__ __launch_bounds__(256) void tail_kernel(
    const h16* __restrict__ ctx, const float* __restrict__ xres,
    const h16* __restrict__ Wo, const float* __restrict__ bo,
    const float* __restrict__ g1, const float* __restrict__ bb1,
    const h16* __restrict__ W1, const float* __restrict__ b1,
    const h16* __restrict__ W2, const float* __restrict__ b2,
    const float* __restrict__ g2, const float* __restrict__ bb2,
    const float* __restrict__ gf, const float* __restrict__ bf,
    const float* __restrict__ Wout, const float* __restrict__ bout,
    float* __restrict__ x_out, h16* __restrict__ xh_out,
    float* __restrict__ out)
{
    __shared__ h16 Xl[32 * 136];     // ctx, then LN1-out fp16
    __shared__ h16 Wl[128 * 136];    // Wo -> W1h0 -> W2h0 -> W1h1 -> W2h1
    __shared__ h16 Al[32 * 136];     // relu activations
    __shared__ float red[32][2][2];

    int tid = threadIdx.x;
    long row0 = (long)blockIdx.x * 32;

    for (int idx = tid; idx < 32 * 16; idx += 256) {
        int r = idx >> 4, c = idx & 15;
        *(uint4*)&Xl[r * 136 + c * 8] = *(const uint4*)&ctx[(row0 + r) * 128 + c * 8];
    }
    for (int idx = tid; idx < 128 * 16; idx += 256) {
        int r = idx >> 4, c = idx & 15;
        *(uint4*)&Wl[r * 136 + c * 8] = *(const uint4*)&Wo[r * 128 + c * 8];
    }
    __syncthreads();                                   // SYNC A

    int lane = tid & 63, w = tid >> 6;
    int lr = lane & 15, lg = lane >> 4;
    int wrow = (w >> 1) * 16, wcol = (w & 1) * 64;
    int cg = w & 1;

    // ---- Wo projection ----
    f32x4 acc[4] = {{0.f,0.f,0.f,0.f},{0.f,0.f,0.f,0.f},
                    {0.f,0.f,0.f,0.f},{0.f,0.f,0.f,0.f}};
    #pragma unroll
    for (int k0 = 0; k0 < 128; k0 += 32) {
        h16x8 af = *(const h16x8*)&Xl[(wrow + lr) * 136 + k0 + lg * 8];
        #pragma unroll
        for (int n = 0; n < 4; ++n) {
            h16x8 bfr = *(const h16x8*)&Wl[(wcol + 16 * n + lr) * 136 + k0 + lg * 8];
            acc[n] = __builtin_amdgcn_mfma_f32_16x16x32_f16(af, bfr, acc[n], 0, 0, 0);
        }
    }

    // ---- LN1 (result kept in registers) ----
    float val1[4][4];
    #pragma unroll
    for (int r = 0; r < 4; ++r) {
        long row = row0 + wrow + lg * 4 + r;
        #pragma unroll
        for (int n = 0; n < 4; ++n) {
            int col = wcol + 16 * n + lr;
            val1[r][n] = acc[n][r] + bo[col] + xres[row * 128 + col];
        }
    }
    #pragma unroll
    for (int r = 0; r < 4; ++r) {
        float s  = val1[r][0] + val1[r][1] + val1[r][2] + val1[r][3];
        float sq = val1[r][0]*val1[r][0] + val1[r][1]*val1[r][1]
                 + val1[r][2]*val1[r][2] + val1[r][3]*val1[r][3];
        #pragma unroll
        for (int m = 1; m < 16; m <<= 1) {
            s  += __shfl_xor(s, m);
            sq += __shfl_xor(sq, m);
        }
        if (lr == 0) {
            red[wrow + lg * 4 + r][cg][0] = s;
            red[wrow + lg * 4 + r][cg][1] = sq;
        }
    }
    __syncthreads();                                   // SYNC B
    #pragma unroll
    for (int r = 0; r < 4; ++r) {
        int rowt = wrow + lg * 4 + r;
        float S  = red[rowt][0][0] + red[rowt][1][0];
        float SQ = red[rowt][0][1] + red[rowt][1][1];
        float mean = S * (1.0f / 128.0f);
        float var  = SQ * (1.0f / 128.0f) - mean * mean;
        float rstd = rsqrtf(var + EPSV);
        #pragma unroll
        for (int n = 0; n < 4; ++n) {
            int col = wcol + 16 * n + lr;
            val1[r][n] = (val1[r][n] - mean) * rstd * g1[col] + bb1[col];
        }
    }
    // LN1 out -> Xl (fp16); overwrites ctx (all reads completed before SYNC B)
    #pragma unroll
    for (int r = 0; r < 4; ++r)
        #pragma unroll
        for (int n = 0; n < 4; ++n)
            Xl[(wrow + lg * 4 + r) * 136 + wcol + 16 * n + lr] = (h16)val1[r][n];

    f32x4 acc2[4] = {{0.f,0.f,0.f,0.f},{0.f,0.f,0.f,0.f},
                     {0.f,0.f,0.f,0.f},{0.f,0.f,0.f,0.f}};

    #pragma unroll 1
    for (int half = 0; half < 2; ++half) {
        // stage W1 half (Wl reads completed before previous barrier)
        for (int idx = tid; idx < 128 * 16; idx += 256) {
            int r = idx >> 4, c = idx & 15;
            *(uint4*)&Wl[r * 136 + c * 8] =
                *(const uint4*)&W1[(long)(128 * half + r) * 128 + c * 8];
        }
        __syncthreads();                               // SYNC C/G

        // FF1 half: a = x1 @ W1h^T
        f32x4 a1[4] = {{0.f,0.f,0.f,0.f},{0.f,0.f,0.f,0.f},
                       {0.f,0.f,0.f,0.f},{0.f,0.f,0.f,0.f}};
        #pragma unroll
        for (int k0 = 0; k0 < 128; k0 += 32) {
            h16x8 af = *(const h16x8*)&Xl[(wrow + lr) * 136 + k0 + lg * 8];
            #pragma unroll
            for (int n = 0; n < 4; ++n) {
                h16x8 bfr = *(const h16x8*)&Wl[(wcol + 16 * n + lr) * 136 + k0 + lg * 8];
                a1[n] = __builtin_amdgcn_mfma_f32_16x16x32_f16(af, bfr, a1[n], 0, 0, 0);
            }
        }
        __syncthreads();                               // SYNC D/H

        // Al = relu(a1 + b1) fp16; stage W2 half
        #pragma unroll
        for (int r = 0; r < 4; ++r)
            #pragma unroll
            for (int n = 0; n < 4; ++n) {
                int col = wcol + 16 * n + lr;
                float v = a1[n][r] + b1[128 * half + col];
                Al[(wrow + lg * 4 + r) * 136 + col] = (h16)fmaxf(v, 0.f);
            }
        for (int idx = tid; idx < 128 * 16; idx += 256) {
            int r = idx >> 4, c = idx & 15;
            *(uint4*)&Wl[r * 136 + c * 8] =
                *(const uint4*)&W2[(long)r * 256 + 128 * half + c * 8];
        }
        __syncthreads();                               // SYNC E/I

        // FF2 half: acc2 += a @ W2h^T
        #pragma unroll
        for (int k0 = 0; k0 < 128; k0 += 32) {
            h16x8 af = *(const h16x8*)&Al[(wrow + lr) * 136 + k0 + lg * 8];
            #pragma unroll
            for (int n = 0; n < 4; ++n) {
                h16x8 bfr = *(const h16x8*)&Wl[(wcol + 16 * n + lr) * 136 + k0 + lg * 8];
                acc2[n] = __builtin_amdgcn_mfma_f32_16x16x32_f16(af, bfr, acc2[n], 0, 0, 0);
            }
        }
        __syncthreads();                               // SYNC F/J (Wl/Al reads done)
    }

    // ---- LN2 (residual = LN1 output in registers) ----
    float val2[4][4];
    #pragma unroll
    for (int r = 0; r < 4; ++r)
        #pragma unroll
        for (int n = 0; n < 4; ++n) {
            int col = wcol + 16 * n + lr;
            val2[r][n] = acc2[n][r] + b2[col] + val1[r][n];
        }
    #pragma unroll
    for (int r = 0; r < 4; ++r) {
        float s  = val2[r][0] + val2[r][1] + val2[r][2] + val2[r][3];
        float sq = val2[r][0]*val2[r][0] + val2[r][1]*val2[r][1]
                 + val2[r][2]*val2[r][2] + val2[r][3]*val2[r][3];
        #pragma unroll
        for (int m = 1; m < 16; m <<= 1) {
            s  += __shfl_xor(s, m);
            sq += __shfl_xor(sq, m);
        }
        if (lr == 0) {
            red[wrow + lg * 4 + r][cg][0] = s;
            red[wrow + lg * 4 + r][cg][1] = sq;
        }
    }
    __syncthreads();                                   // SYNC K
    #pragma unroll
    for (int r = 0; r < 4; ++r) {
        int rowt = wrow + lg * 4 + r;
        float S  = red[rowt][0][0] + red[rowt][1][0];
        float SQ = red[rowt][0][1] + red[rowt][1][1];
        float mean = S * (1.0f / 128.0f);
        float var  = SQ * (1.0f / 128.0f) - mean * mean;
        float rstd = rsqrtf(var + EPSV);
        #pragma unroll
        for (int n = 0; n < 4; ++n) {
            int col = wcol + 16 * n + lr;
            val2[r][n] = (val2[r][n] - mean) * rstd * g2[col] + bb2[col];
        }
    }

    if (!LAST) {
        #pragma unroll
        for (int r = 0; r < 4; ++r) {
            long row = row0 + wrow + lg * 4 + r;
            #pragma unroll
            for (int n = 0; n < 4; ++n) {
                int col = wcol + 16 * n + lr;
                x_out[row * 128 + col]  = val2[r][n];
                xh_out[row * 128 + col] = (h16)val2[r][n];
            }
        }
    } else {
        // ---- final LN + out-projection + softplus ----
        __syncthreads();                               // red reads done
        #pragma unroll
        for (int r = 0; r < 4; ++r) {
            float s  = val2[r][0] + val2[r][1] + val2[r][2] + val2[r][3];
            float sq = val2[r][0]*val2[r][0] + val2[r][1]*val2[r][1]
                     + val2[r][2]*val2[r][2] + val2[r][3]*val2[r][3];
            #pragma unroll
            for (int m = 1; m < 16; m <<= 1) {
                s  += __shfl_xor(s, m);
                sq += __shfl_xor(sq, m);
            }
            if (lr == 0) {
                red[wrow + lg * 4 + r][cg][0] = s;
                red[wrow + lg * 4 + r][cg][1] = sq;
            }
        }
        __syncthreads();
        float dotp[4];
        #pragma unroll
        for (int r = 0; r < 4; ++r) {
            int rowt = wrow + lg * 4 + r;
            float S  = red[rowt][0][0] + red[rowt][1][0];
            float SQ = red[rowt][0][1] + red[rowt][1][1];
            float mean = S * (1.0f / 128.0f);
            float var  = SQ * (1.0f / 128.0f) - mean * mean;
            float rstd = rsqrtf(var + EPSV);
            float d = 0.f;
            #pragma unroll
            for (int n = 0; n < 4; ++n) {
                int col = wcol + 16 * n + lr;
                float nf = (val2[r][n] - mean) * rstd * gf[col] + bf[col];
                d = fmaf(nf, Wout[col], d);
            }
            #pragma unroll
            for (int m = 1; m < 16; m <<= 1) d += __shfl_xor(d, m);
            dotp[r] = d;
        }
        __syncthreads();                               // red reads done
        #pragma unroll
        for (int r = 0; r < 4; ++r)
            if (lr == 0) red[wrow + lg * 4 + r][cg][0] = dotp[r];
        __syncthreads();
        if (tid < 32) {
            float z = red[tid][0][0] + red[tid][1][0] + bout[0];
            out[row0 + tid] = fmaxf(z, 0.f) + log1pf(__expf(-fabsf(z)));
        }
    }
}

// ---------------------------------------------------------------------------
extern "C" void kernel_launch(void* const* d_in, const int* in_sizes, int n_in,
                              void* d_out, int out_size, void* d_ws, size_t ws_size,
                              hipStream_t stream)
{
    const int*   tok  = (const int*)d_in[0];
    const float* emb  = (const float*)d_in[1];
    const float* Wqkv = (const float*)d_in[2];
    const float* bqkv = (const float*)d_in[3];
    const float* Wo   = (const float*)d_in[4];
    const float* bo   = (const float*)d_in[5];
    const float* ln1g = (const float*)d_in[6];
    const float* ln1b = (const float*)d_in[7];
    const float* ln2g = (const float*)d_in[8];
    const float* ln2b = (const float*)d_in[9];
    const float* W1   = (const float*)d_in[10];
    const float* b1   = (const float*)d_in[11];
    const float* W2   = (const float*)d_in[12];
    const float* b2   = (const float*)d_in[13];
    const float* lnfg = (const float*)d_in[14];
    const float* lnfb = (const float*)d_in[15];
    const float* Wout = (const float*)d_in[16];
    const float* bout = (const float*)d_in[17];
    float* out = (float*)d_out;

    char* wsb = (char*)d_ws;
    float* x    = (float*)wsb;                        // NT*128 f32   (4 MB)
    h16*   xh   = (h16*)(wsb + 4194304);              // NT*128 h16   (2 MB)
    h16*   qkvh = (h16*)(wsb + 6291456);              // NT*384 h16   (6 MB)
    h16*   ctxh = (h16*)(wsb + 12582912);             // NT*128 h16   (2 MB)
    h16*   wh   = (h16*)(wsb + 14680064);             // 524288 h16   (1 MB)

    h16* Wqkv_h = wh + WQKV_OFF;
    h16* Wo_h   = wh + WO_OFF;
    h16* W1_h   = wh + W1_OFF;
    h16* W2_h   = wh + W2_OFF;

    prep_kernel<<<4096 + WTOT / 1024, 256, 0, stream>>>(
        tok, emb, x, xh, Wqkv, Wo, W1, W2, wh);

    for (int l = 0; l < NL; ++l) {
        gemm16_kernel<<<dim3(NT / 64, 384 / 64), 256, 0, stream>>>(
            xh, Wqkv_h + (size_t)l * 384 * 128, bqkv + l * 384, qkvh, 384);
        attn16_kernel<<<BATCH * NH * (SEQ / 64), 256, 0, stream>>>(qkvh, ctxh);
        if (l < NL - 1) {
            tail_kernel<0><<<NT / 32, 256, 0, stream>>>(
                ctxh, x,
                Wo_h + (size_t)l * 128 * 128, bo + l * 128,
                ln1g + l * DM, ln1b + l * DM,
                W1_h + (size_t)l * 256 * 128, b1 + l * 256,
                W2_h + (size_t)l * 128 * 256, b2 + l * 128,
                ln2g + l * DM, ln2b + l * DM,
                lnfg, lnfb, Wout, bout,
                x, xh, out);
        } else {
            tail_kernel<1><<<NT / 32, 256, 0, stream>>>(
                ctxh, x,
                Wo_h + (size_t)l * 128 * 128, bo + l * 128,
                ln1g + l * DM, ln1b + l * DM,
                W1_h + (size_t)l * 256 * 128, b1 + l * 256,
                W2_h + (size_t)l * 128 * 256, b2 + l * 128,
                ln2g + l * DM, ln2b + l * DM,
                lnfg, lnfb, Wout, bout,
                x, xh, out);
        }
    }
}

// Round 7
// 225.697 us; speedup vs baseline: 2.1625x; 1.0860x over previous
//
#include <hip/hip_runtime.h>
#include <hip/hip_bf16.h>
#include <math.h>

#define NL   4
#define NH   8
#define DM   128
#define FFD  256
#define SEQ  1024
#define BATCH 8
#define NT   (BATCH*SEQ)      // 8192 tokens
#define EPSV 1e-5f

typedef _Float16 h16;
typedef h16   h16x8 __attribute__((ext_vector_type(8)));
typedef float f32x4 __attribute__((ext_vector_type(4)));

// fp16 weight buffer segment offsets (elements)
#define WQKV_OFF 0
#define WO_OFF   196608
#define W1_OFF   262144
#define W2_OFF   393216
#define WTOT     524288

// ---------------------------------------------------------------------------
// Fused prep: embed+PE (blocks 0..4095) and weight fp32->fp16 (blocks 4096+)
// ---------------------------------------------------------------------------
__global__ __launch_bounds__(256) void prep_kernel(
    const int* __restrict__ tok, const float* __restrict__ emb,
    float* __restrict__ x, h16* __restrict__ xh,
    const float* __restrict__ wqkv, const float* __restrict__ wo,
    const float* __restrict__ w1, const float* __restrict__ w2,
    h16* __restrict__ wdst)
{
    int bid = blockIdx.x;
    if (bid < 4096) {
        int idx = bid * 256 + threadIdx.x;
        int t = idx >> 7;
        int d = idx & 127;
        int s = t & (SEQ - 1);
        int token = tok[t];
        float freq = expf((float)(d & ~1) * (-9.210340371976184f / 128.0f));
        float ang = (float)s * freq;
        float pe = (d & 1) ? cosf(ang) : sinf(ang);
        float v = emb[token * DM + d] + pe;
        x[idx] = v;
        xh[idx] = (h16)v;
    } else {
        int i = ((bid - 4096) * 256 + threadIdx.x) * 4;
        const float* src; int off;
        if (i < WO_OFF)      { src = wqkv; off = 0; }
        else if (i < W1_OFF) { src = wo;   off = WO_OFF; }
        else if (i < W2_OFF) { src = w1;   off = W1_OFF; }
        else                 { src = w2;   off = W2_OFF; }
        float4 v = *(const float4*)&src[i - off];
        h16 o[4] = {(h16)v.x, (h16)v.y, (h16)v.z, (h16)v.w};
        *(uint2*)&wdst[i] = *(uint2*)o;
    }
}

// ---------------------------------------------------------------------------
// fp16 MFMA GEMM (QKV): C = A[M,128] @ W[N,128]^T + bias -> fp16. (proven)
// ---------------------------------------------------------------------------
__global__ __launch_bounds__(256) void gemm16_kernel(
    const h16* __restrict__ A, const h16* __restrict__ W,
    const float* __restrict__ bias, h16* __restrict__ out16, int N)
{
    __shared__ h16 Al[64 * 136];
    __shared__ h16 Wl[64 * 136];

    int tid = threadIdx.x;
    long row0 = (long)blockIdx.x * 64;
    long col0 = (long)blockIdx.y * 64;

    for (int idx = tid; idx < 64 * 16; idx += 256) {
        int r = idx >> 4, c = idx & 15;
        *(uint4*)&Al[r * 136 + c * 8] = *(const uint4*)&A[(row0 + r) * 128 + c * 8];
        *(uint4*)&Wl[r * 136 + c * 8] = *(const uint4*)&W[(col0 + r) * 128 + c * 8];
    }
    __syncthreads();

    int lane = tid & 63, wv = tid >> 6;
    int lr = lane & 15, lg = lane >> 4;
    int wr = (wv >> 1) * 32, wc = (wv & 1) * 32;

    f32x4 acc[2][2] = {{{0.f,0.f,0.f,0.f},{0.f,0.f,0.f,0.f}},
                       {{0.f,0.f,0.f,0.f},{0.f,0.f,0.f,0.f}}};

    #pragma unroll
    for (int k0 = 0; k0 < 128; k0 += 32) {
        h16x8 a0 = *(const h16x8*)&Al[(wr +      lr) * 136 + k0 + lg * 8];
        h16x8 a1 = *(const h16x8*)&Al[(wr + 16 + lr) * 136 + k0 + lg * 8];
        h16x8 b0 = *(const h16x8*)&Wl[(wc +      lr) * 136 + k0 + lg * 8];
        h16x8 b1 = *(const h16x8*)&Wl[(wc + 16 + lr) * 136 + k0 + lg * 8];
        acc[0][0] = __builtin_amdgcn_mfma_f32_16x16x32_f16(a0, b0, acc[0][0], 0, 0, 0);
        acc[0][1] = __builtin_amdgcn_mfma_f32_16x16x32_f16(a0, b1, acc[0][1], 0, 0, 0);
        acc[1][0] = __builtin_amdgcn_mfma_f32_16x16x32_f16(a1, b0, acc[1][0], 0, 0, 0);
        acc[1][1] = __builtin_amdgcn_mfma_f32_16x16x32_f16(a1, b1, acc[1][1], 0, 0, 0);
    }

    #pragma unroll
    for (int m = 0; m < 2; ++m)
    #pragma unroll
    for (int n = 0; n < 2; ++n) {
        long col = col0 + wc + 16 * n + lr;
        float bv = bias[col];
        #pragma unroll
        for (int r = 0; r < 4; ++r) {
            long row = row0 + wr + 16 * m + lg * 4 + r;
            out16[row * N + col] = (h16)(acc[m][n][r] + bv);
        }
    }
}

// ---------------------------------------------------------------------------
// MFMA banded attention. Same math as proven version; P now streamed through
// a half-size per-wave LDS buffer (two PV passes, chunk order preserved ->
// bitwise-identical output). LDS 63.5 -> 47.5 KB => 3 blocks/CU.
// In-wave DS ordering guarantees P-write(half B) cannot pass P-read(half A).
// ---------------------------------------------------------------------------
#define NSLOT 336
#define KSTR  24
#define VSTR  344
#define PSTR2 168

__global__ __launch_bounds__(256) void attn16_kernel(
    const h16* __restrict__ qkvh, h16* __restrict__ ctxh)
{
    __shared__ h16 Kl[NSLOT * KSTR];     // 16128 B
    __shared__ h16 Vt[16 * VSTR];        // 11008 B
    __shared__ h16 Pl[4 * 16 * PSTR2];   // 21504 B

    int tid = threadIdx.x;
    int blk = blockIdx.x;
    int qb = blk & 15;
    int h  = (blk >> 4) & 7;
    int b  = blk >> 7;
    int q0b = qb * 64;
    int kw0 = q0b - 128;

    for (int idx = tid; idx < NSLOT * 2; idx += 256) {
        int slot = idx >> 1, part = (idx & 1) * 8;
        int ka = kw0 + slot;
        uint4 val = {0u, 0u, 0u, 0u};
        if (ka >= 0 && ka < SEQ)
            val = *(const uint4*)&qkvh[((size_t)(b * SEQ + ka)) * 384 + h * 16 + 128 + part];
        *(uint4*)&Kl[slot * KSTR + part] = val;
    }
    for (int idx = tid; idx < NSLOT * 2; idx += 256) {
        int slot = idx >> 1, part = (idx & 1) * 8;
        int ka = kw0 + slot;
        uint4 val = {0u, 0u, 0u, 0u};
        if (ka >= 0 && ka < SEQ)
            val = *(const uint4*)&qkvh[((size_t)(b * SEQ + ka)) * 384 + h * 16 + 256 + part];
        h16 tmp[8];
        *(uint4*)tmp = val;
        #pragma unroll
        for (int j = 0; j < 8; ++j)
            Vt[(part + j) * VSTR + slot] = tmp[j];
    }
    __syncthreads();

    int lane = tid & 63, w = tid >> 6;
    int lr = lane & 15, lg = lane >> 4;
    int q0w = q0b + w * 16;

    h16x8 qf = {0, 0, 0, 0, 0, 0, 0, 0};
    if (lg < 2)
        qf = *(const h16x8*)&qkvh[((size_t)(b * SEQ + q0w + lr)) * 384 + h * 16 + lg * 8];
    qf = qf * (h16)0.25f;

    f32x4 s[17];
    const f32x4 zero4 = {0.f, 0.f, 0.f, 0.f};
    #pragma unroll
    for (int t = 0; t < 17; ++t) {
        h16x8 kf = {0, 0, 0, 0, 0, 0, 0, 0};
        if (lg < 2)
            kf = *(const h16x8*)&Kl[(w * 16 + t * 16 + lr) * KSTR + lg * 8];
        s[t] = __builtin_amdgcn_mfma_f32_16x16x32_f16(qf, kf, zero4, 0, 0, 0);
    }

    bool interior = (q0b >= 128) && (q0b <= 832);
    if (interior) {
        #pragma unroll
        for (int r = 0; r < 4; ++r) {
            int qr = lg * 4 + r;
            if (lr < qr) s[0][r]  = -1e30f;
            if (lr > qr) s[16][r] = -1e30f;
        }
    } else {
        #pragma unroll
        for (int t = 0; t < 17; ++t)
        #pragma unroll
        for (int r = 0; r < 4; ++r) {
            int rel = 16 * t + lr - (lg * 4 + r);
            int ka  = kw0 + w * 16 + 16 * t + lr;
            bool valid = (rel >= 0) && (rel <= 256) && (ka >= 0) && (ka < SEQ);
            if (!valid) s[t][r] = -1e30f;
        }
    }

    float mx[4] = {-1e30f, -1e30f, -1e30f, -1e30f};
    #pragma unroll
    for (int t = 0; t < 17; ++t)
        #pragma unroll
        for (int r = 0; r < 4; ++r) mx[r] = fmaxf(mx[r], s[t][r]);
    #pragma unroll
    for (int r = 0; r < 4; ++r) {
        mx[r] = fmaxf(mx[r], __shfl_xor(mx[r], 1));
        mx[r] = fmaxf(mx[r], __shfl_xor(mx[r], 2));
        mx[r] = fmaxf(mx[r], __shfl_xor(mx[r], 4));
        mx[r] = fmaxf(mx[r], __shfl_xor(mx[r], 8));
    }
    float sum[4] = {0.f, 0.f, 0.f, 0.f};
    #pragma unroll
    for (int t = 0; t < 17; ++t)
        #pragma unroll
        for (int r = 0; r < 4; ++r) {
            float p = __expf(s[t][r] - mx[r]);
            s[t][r] = p;
            sum[r] += p;
        }
    #pragma unroll
    for (int r = 0; r < 4; ++r) {
        sum[r] += __shfl_xor(sum[r], 1);
        sum[r] += __shfl_xor(sum[r], 2);
        sum[r] += __shfl_xor(sum[r], 4);
        sum[r] += __shfl_xor(sum[r], 8);
    }

    h16* Pw = &Pl[w * 16 * PSTR2];
    f32x4 o = {0.f, 0.f, 0.f, 0.f};

    // ---- half A: tiles 0..9 (window keys 0..159 = chunks 0..4) ----
    #pragma unroll
    for (int t = 0; t < 10; ++t)
        #pragma unroll
        for (int r = 0; r < 4; ++r)
            Pw[(lg * 4 + r) * PSTR2 + t * 16 + lr] = (h16)s[t][r];
    #pragma unroll
    for (int c = 0; c < 5; ++c) {
        h16x8 pf = *(const h16x8*)&Pw[lr * PSTR2 + c * 32 + lg * 8];
        h16x8 vf = *(const h16x8*)&Vt[lr * VSTR + w * 16 + c * 32 + lg * 8];
        o = __builtin_amdgcn_mfma_f32_16x16x32_f16(pf, vf, o, 0, 0, 0);
    }
    // ---- half B: tiles 10..16 + zero pad (keys 160..287 = chunks 5..8) ----
    #pragma unroll
    for (int t = 10; t < 17; ++t)
        #pragma unroll
        for (int r = 0; r < 4; ++r)
            Pw[(lg * 4 + r) * PSTR2 + (t - 10) * 16 + lr] = (h16)s[t][r];
    #pragma unroll
    for (int r = 0; r < 4; ++r)
        Pw[(lg * 4 + r) * PSTR2 + 112 + lr] = (h16)0.f;
    #pragma unroll
    for (int c = 0; c < 4; ++c) {
        h16x8 pf = *(const h16x8*)&Pw[lr * PSTR2 + c * 32 + lg * 8];
        h16x8 vf = *(const h16x8*)&Vt[lr * VSTR + w * 16 + (c + 5) * 32 + lg * 8];
        o = __builtin_amdgcn_mfma_f32_16x16x32_f16(pf, vf, o, 0, 0, 0);
    }

    #pragma unroll
    for (int r = 0; r < 4; ++r) {
        float val = o[r] / sum[r];
        ctxh[((size_t)(b * SEQ + q0w + lg * 4 + r)) * DM + h * 16 + lr] = (h16)val;
    }
}

// ---------------------------------------------------------------------------
// Fused layer tail, 512 threads (8 waves = 2/SIMD), double-buffered weight
// staging: stage of phase k+1's weights overlaps phase k's MFMA. Hazard
// ledger: stage into buffer X only after the barrier that ends X's last
// reader phase. 7 barriers in the non-LAST path (was 10).
// Wave layout: 2 row-groups x 4 col-groups of 16x32.
// ---------------------------------------------------------------------------
template<int LAST>
__global__ __launch_bounds__(512) void tail_kernel(
    const h16* __restrict__ ctx, const float* __restrict__ xres,
    const h16* __restrict__ Wo, const float* __restrict__ bo,
    const float* __restrict__ g1, const float* __restrict__ bb1,
    const h16* __restrict__ W1, const float* __restrict__ b1,
    const h16* __restrict__ W2, const float* __restrict__ b2,
    const float* __restrict__ g2, const float* __restrict__ bb2,
    const float* __restrict__ gf, const float* __restrict__ bf,
    const float* __restrict__ Wout, const float* __restrict__ bout,
    float* __restrict__ x_out, h16* __restrict__ xh_out,
    float* __restrict__ out)
{
    __shared__ h16 Xl[32 * 136];       // ctx, then LN1-out fp16
    __shared__ h16 Wl[2][128 * 136];   // double-buffered weights
    __shared__ h16 Al[32 * 136];       // relu activations
    __shared__ float red[32][4][2];

    int tid = threadIdx.x;
    long row0 = (long)blockIdx.x * 32;
    int lane = tid & 63, w = tid >> 6;       // w 0..7
    int lr = lane & 15, lg = lane >> 4;
    int wrow = (w >> 2) * 16;                // 0 / 16
    int wcol = (w & 3) * 32;                 // 0,32,64,96
    int cg = w & 3;

    auto stageW = [&](int buf, const h16* src, long rstride, long roff, long coff) {
        #pragma unroll
        for (int it = 0; it < 4; ++it) {
            int idx = tid + it * 512;
            int r = idx >> 4, c = idx & 15;
            *(uint4*)&Wl[buf][r * 136 + c * 8] =
                *(const uint4*)&src[(roff + r) * rstride + coff + c * 8];
        }
    };

    // ---- P0: stage ctx->Xl (512 = 32x16 exactly), Wo->Wl[0] ----
    {
        int r = tid >> 4, c = tid & 15;
        *(uint4*)&Xl[r * 136 + c * 8] = *(const uint4*)&ctx[(row0 + r) * 128 + c * 8];
    }
    stageW(0, Wo, 128, 0, 0);
    __syncthreads();                                    // bar0

    // ---- P1: [stage W1h0->Wl[1]] || Wo MFMA (Xl, Wl[0]) ; LN1 partials ----
    stageW(1, W1, 128, 0, 0);
    f32x4 acc[2] = {{0.f,0.f,0.f,0.f},{0.f,0.f,0.f,0.f}};
    #pragma unroll
    for (int k0 = 0; k0 < 128; k0 += 32) {
        h16x8 af = *(const h16x8*)&Xl[(wrow + lr) * 136 + k0 + lg * 8];
        #pragma unroll
        for (int n = 0; n < 2; ++n) {
            h16x8 bfr = *(const h16x8*)&Wl[0][(wcol + 16 * n + lr) * 136 + k0 + lg * 8];
            acc[n] = __builtin_amdgcn_mfma_f32_16x16x32_f16(af, bfr, acc[n], 0, 0, 0);
        }
    }
    float val1[4][2];
    #pragma unroll
    for (int r = 0; r < 4; ++r) {
        long row = row0 + wrow + lg * 4 + r;
        #pragma unroll
        for (int n = 0; n < 2; ++n) {
            int col = wcol + 16 * n + lr;
            val1[r][n] = acc[n][r] + bo[col] + xres[row * 128 + col];
        }
    }
    #pragma unroll
    for (int r = 0; r < 4; ++r) {
        float s  = val1[r][0] + val1[r][1];
        float sq = val1[r][0]*val1[r][0] + val1[r][1]*val1[r][1];
        #pragma unroll
        for (int m = 1; m < 16; m <<= 1) {
            s  += __shfl_xor(s, m);
            sq += __shfl_xor(sq, m);
        }
        if (lr == 0) {
            red[wrow + lg * 4 + r][cg][0] = s;
            red[wrow + lg * 4 + r][cg][1] = sq;
        }
    }
    __syncthreads();                                    // bar1

    // ---- P2: [stage W2h0->Wl[0]] || LN1 finalize -> Xl fp16 ----
    stageW(0, W2, 256, 0, 0);
    #pragma unroll
    for (int r = 0; r < 4; ++r) {
        int rowt = wrow + lg * 4 + r;
        float S  = red[rowt][0][0] + red[rowt][1][0] + red[rowt][2][0] + red[rowt][3][0];
        float SQ = red[rowt][0][1] + red[rowt][1][1] + red[rowt][2][1] + red[rowt][3][1];
        float mean = S * (1.0f / 128.0f);
        float var  = SQ * (1.0f / 128.0f) - mean * mean;
        float rstd = rsqrtf(var + EPSV);
        #pragma unroll
        for (int n = 0; n < 2; ++n) {
            int col = wcol + 16 * n + lr;
            val1[r][n] = (val1[r][n] - mean) * rstd * g1[col] + bb1[col];
            Xl[rowt * 136 + col] = (h16)val1[r][n];
        }
    }
    __syncthreads();                                    // bar2

    // ---- P3: FF1h0 MFMA (Xl, Wl[1]) ; Al = relu(+b1 h0) ----
    f32x4 a1[2] = {{0.f,0.f,0.f,0.f},{0.f,0.f,0.f,0.f}};
    #pragma unroll
    for (int k0 = 0; k0 < 128; k0 += 32) {
        h16x8 af = *(const h16x8*)&Xl[(wrow + lr) * 136 + k0 + lg * 8];
        #pragma unroll
        for (int n = 0; n < 2; ++n) {
            h16x8 bfr = *(const h16x8*)&Wl[1][(wcol + 16 * n + lr) * 136 + k0 + lg * 8];
            a1[n] = __builtin_amdgcn_mfma_f32_16x16x32_f16(af, bfr, a1[n], 0, 0, 0);
        }
    }
    #pragma unroll
    for (int r = 0; r < 4; ++r)
        #pragma unroll
        for (int n = 0; n < 2; ++n) {
            int col = wcol + 16 * n + lr;
            float v = a1[n][r] + b1[col];
            Al[(wrow + lg * 4 + r) * 136 + col] = (h16)fmaxf(v, 0.f);
        }
    __syncthreads();                                    // bar3

    // ---- P4: [stage W1h1->Wl[1]] || FF2h0 MFMA (Al, Wl[0]) ----
    stageW(1, W1, 128, 128, 0);
    f32x4 acc2[2] = {{0.f,0.f,0.f,0.f},{0.f,0.f,0.f,0.f}};
    #pragma unroll
    for (int k0 = 0; k0 < 128; k0 += 32) {
        h16x8 af = *(const h16x8*)&Al[(wrow + lr) * 136 + k0 + lg * 8];
        #pragma unroll
        for (int n = 0; n < 2; ++n) {
            h16x8 bfr = *(const h16x8*)&Wl[0][(wcol + 16 * n + lr) * 136 + k0 + lg * 8];
            acc2[n] = __builtin_amdgcn_mfma_f32_16x16x32_f16(af, bfr, acc2[n], 0, 0, 0);
        }
    }
    __syncthreads();                                    // bar4

    // ---- P5: [stage W2h1->Wl[0]] || FF1h1 MFMA (Xl, Wl[1]) ; Al=relu(+b1 h1) ----
    stageW(0, W2, 256, 0, 128);
    #pragma unroll
    for (int n = 0; n < 2; ++n) a1[n] = f32x4{0.f,0.f,0.f,0.f};
    #pragma unroll
    for (int k0 = 0; k0 < 128; k0 += 32) {
        h16x8 af = *(const h16x8*)&Xl[(wrow + lr) * 136 + k0 + lg * 8];
        #pragma unroll
        for (int n = 0; n < 2; ++n) {
            h16x8 bfr = *(const h16x8*)&Wl[1][(wcol + 16 * n + lr) * 136 + k0 + lg * 8];
            a1[n] = __builtin_amdgcn_mfma_f32_16x16x32_f16(af, bfr, a1[n], 0, 0, 0);
        }
    }
    #pragma unroll
    for (int r = 0; r < 4; ++r)
        #pragma unroll
        for (int n = 0; n < 2; ++n) {
            int col = wcol + 16 * n + lr;
            float v = a1[n][r] + b1[128 + col];
            Al[(wrow + lg * 4 + r) * 136 + col] = (h16)fmaxf(v, 0.f);
        }
    __syncthreads();                                    // bar5

    // ---- P6: FF2h1 MFMA (Al, Wl[0]) ; LN2 partials ----
    #pragma unroll
    for (int k0 = 0; k0 < 128; k0 += 32) {
        h16x8 af = *(const h16x8*)&Al[(wrow + lr) * 136 + k0 + lg * 8];
        #pragma unroll
        for (int n = 0; n < 2; ++n) {
            h16x8 bfr = *(const h16x8*)&Wl[0][(wcol + 16 * n + lr) * 136 + k0 + lg * 8];
            acc2[n] = __builtin_amdgcn_mfma_f32_16x16x32_f16(af, bfr, acc2[n], 0, 0, 0);
        }
    }
    float val2[4][2];
    #pragma unroll
    for (int r = 0; r < 4; ++r)
        #pragma unroll
        for (int n = 0; n < 2; ++n) {
            int col = wcol + 16 * n + lr;
            val2[r][n] = acc2[n][r] + b2[col] + val1[r][n];
        }
    #pragma unroll
    for (int r = 0; r < 4; ++r) {
        float s  = val2[r][0] + val2[r][1];
        float sq = val2[r][0]*val2[r][0] + val2[r][1]*val2[r][1];
        #pragma unroll
        for (int m = 1; m < 16; m <<= 1) {
            s  += __shfl_xor(s, m);
            sq += __shfl_xor(sq, m);
        }
        if (lr == 0) {
            red[wrow + lg * 4 + r][cg][0] = s;
            red[wrow + lg * 4 + r][cg][1] = sq;
        }
    }
    __syncthreads();                                    // bar6

    // ---- P7: LN2 finalize ----
    #pragma unroll
    for (int r = 0; r < 4; ++r) {
        int rowt = wrow + lg * 4 + r;
        float S  = red[rowt][0][0] + red[rowt][1][0] + red[rowt][2][0] + red[rowt][3][0];
        float SQ = red[rowt][0][1] + red[rowt][1][1] + red[rowt][2][1] + red[rowt][3][1];
        float mean = S * (1.0f / 128.0f);
        float var  = SQ * (1.0f / 128.0f) - mean * mean;
        float rstd = rsqrtf(var + EPSV);
        #pragma unroll
        for (int n = 0; n < 2; ++n) {
            int col = wcol + 16 * n + lr;
            val2[r][n] = (val2[r][n] - mean) * rstd * g2[col] + bb2[col];
        }
    }

    if (!LAST) {
        #pragma unroll
        for (int r = 0; r < 4; ++r) {
            long row = row0 + wrow + lg * 4 + r;
            #pragma unroll
            for (int n = 0; n < 2; ++n) {
                int col = wcol + 16 * n + lr;
                x_out[row * 128 + col]  = val2[r][n];
                xh_out[row * 128 + col] = (h16)val2[r][n];
            }
        }
    } else {
        // ---- final LN + out-projection + softplus ----
        __syncthreads();                                // red reads done
        #pragma unroll
        for (int r = 0; r < 4; ++r) {
            float s  = val2[r][0] + val2[r][1];
            float sq = val2[r][0]*val2[r][0] + val2[r][1]*val2[r][1];
            #pragma unroll
            for (int m = 1; m < 16; m <<= 1) {
                s  += __shfl_xor(s, m);
                sq += __shfl_xor(sq, m);
            }
            if (lr == 0) {
                red[wrow + lg * 4 + r][cg][0] = s;
                red[wrow + lg * 4 + r][cg][1] = sq;
            }
        }
        __syncthreads();
        float dotp[4];
        #pragma unroll
        for (int r = 0; r < 4; ++r) {
            int rowt = wrow + lg * 4 + r;
            float S  = red[rowt][0][0] + red[rowt][1][0] + red[rowt][2][0] + red[rowt][3][0];
            float SQ = red[rowt][0][1] + red[rowt][1][1] + red[rowt][2][1] + red[rowt][3][1];
            float mean = S * (1.0f / 128.0f);
            float var  = SQ * (1.0f / 128.0f) - mean * mean;
            float rstd = rsqrtf(var + EPSV);
            float d = 0.f;
            #pragma unroll
            for (int n = 0; n < 2; ++n) {
                int col = wcol + 16 * n + lr;
                float nf = (val2[r][n] - mean) * rstd * gf[col] + bf[col];
                d = fmaf(nf, Wout[col], d);
            }
            #pragma unroll
            for (int m = 1; m < 16; m <<= 1) d += __shfl_xor(d, m);
            dotp[r] = d;
        }
        __syncthreads();                                // red reads done
        #pragma unroll
        for (int r = 0; r < 4; ++r)
            if (lr == 0) red[wrow + lg * 4 + r][cg][0] = dotp[r];
        __syncthreads();
        if (tid < 32) {
            float z = red[tid][0][0] + red[tid][1][0] + red[tid][2][0] + red[tid][3][0] + bout[0];
            out[row0 + tid] = fmaxf(z, 0.f) + log1pf(__expf(-fabsf(z)));
        }
    }
}

// ---------------------------------------------------------------------------
extern "C" void kernel_launch(void* const* d_in, const int* in_sizes, int n_in,
                              void* d_out, int out_size, void* d_ws, size_t ws_size,
                              hipStream_t stream)
{
    const int*   tok  = (const int*)d_in[0];
    const float* emb  = (const float*)d_in[1];
    const float* Wqkv = (const float*)d_in[2];
    const float* bqkv = (const float*)d_in[3];
    const float* Wo   = (const float*)d_in[4];
    const float* bo   = (const float*)d_in[5];
    const float* ln1g = (const float*)d_in[6];
    const float* ln1b = (const float*)d_in[7];
    const float* ln2g = (const float*)d_in[8];
    const float* ln2b = (const float*)d_in[9];
    const float* W1   = (const float*)d_in[10];
    const float* b1   = (const float*)d_in[11];
    const float* W2   = (const float*)d_in[12];
    const float* b2   = (const float*)d_in[13];
    const float* lnfg = (const float*)d_in[14];
    const float* lnfb = (const float*)d_in[15];
    const float* Wout = (const float*)d_in[16];
    const float* bout = (const float*)d_in[17];
    float* out = (float*)d_out;

    char* wsb = (char*)d_ws;
    float* x    = (float*)wsb;                        // NT*128 f32   (4 MB)
    h16*   xh   = (h16*)(wsb + 4194304);              // NT*128 h16   (2 MB)
    h16*   qkvh = (h16*)(wsb + 6291456);              // NT*384 h16   (6 MB)
    h16*   ctxh = (h16*)(wsb + 12582912);             // NT*128 h16   (2 MB)
    h16*   wh   = (h16*)(wsb + 14680064);             // 524288 h16   (1 MB)

    h16* Wqkv_h = wh + WQKV_OFF;
    h16* Wo_h   = wh + WO_OFF;
    h16* W1_h   = wh + W1_OFF;
    h16* W2_h   = wh + W2_OFF;

    prep_kernel<<<4096 + WTOT / 1024, 256, 0, stream>>>(
        tok, emb, x, xh, Wqkv, Wo, W1, W2, wh);

    for (int l = 0; l < NL; ++l) {
        gemm16_kernel<<<dim3(NT / 64, 384 / 64), 256, 0, stream>>>(
            xh, Wqkv_h + (size_t)l * 384 * 128, bqkv + l * 384, qkvh, 384);
        attn16_kernel<<<BATCH * NH * (SEQ / 64), 256, 0, stream>>>(qkvh, ctxh);
        if (l < NL - 1) {
            tail_kernel<0><<<NT / 32, 512, 0, stream>>>(
                ctxh, x,
                Wo_h + (size_t)l * 128 * 128, bo + l * 128,
                ln1g + l * DM, ln1b + l * DM,
                W1_h + (size_t)l * 256 * 128, b1 + l * 256,
                W2_h + (size_t)l * 128 * 256, b2 + l * 128,
                ln2g + l * DM, ln2b + l * DM,
                lnfg, lnfb, Wout, bout,
                x, xh, out);
        } else {
            tail_kernel<1><<<NT / 32, 512, 0, stream>>>(
                ctxh, x,
                Wo_h + (size_t)l * 128 * 128, bo + l * 128,
                ln1g + l * DM, ln1b + l * DM,
                W1_h + (size_t)l * 256 * 128, b1 + l * 256,
                W2_h + (size_t)l * 128 * 256, b2 + l * 128,
                ln2g + l * DM, ln2b + l * DM,
                lnfg, lnfb, Wout, bout,
                x, xh, out);
        }
    }
}